// Round 16
// baseline (350.071 us; speedup 1.0000x reference)
//
#include <hip/hip_runtime.h>
#include <hip/hip_bf16.h>

#define DEVI __device__ __forceinline__

typedef __attribute__((ext_vector_type(8))) short shortx8;
typedef __attribute__((ext_vector_type(4))) float floatx4;

static constexpr int Bsz = 32768, Din = 512, H1 = 512, H2 = 256, NE = 8, Lout = 32;

DEVI float bf2f(short s) {
  union { unsigned u; float f; } c;
  c.u = ((unsigned)(unsigned short)s) << 16;
  return c.f;
}
// round-to-nearest-even f32 -> bf16 (finite inputs only)
DEVI short f2bf(float f) {
  union { float f; unsigned u; } c; c.f = f;
  unsigned u = c.u + (0x7FFFu + ((c.u >> 16) & 1u));
  return (short)(u >> 16);
}

// ---------------- elementwise cast f32 -> bf16 ----------------
__global__ void cast_bf16_kernel(const float* __restrict__ in, short* __restrict__ out, int n4) {
  int stride = gridDim.x * blockDim.x;
  for (int i = blockIdx.x * blockDim.x + threadIdx.x; i < n4; i += stride) {
    float4 v = ((const float4*)in)[i];
    short4 o;
    o.x = f2bf(v.x); o.y = f2bf(v.y); o.z = f2bf(v.z); o.w = f2bf(v.w);
    ((short4*)out)[i] = o;
  }
}

// ---------------- small prep: gW3pad (16 rows, 8 real + 8 zero) + bias concats ----------------
__global__ void prep_small_kernel(const float* __restrict__ gW3,
                                  const float* __restrict__ gb1, const float* __restrict__ eb1,
                                  const float* __restrict__ gb2, const float* __restrict__ eb2,
                                  short* __restrict__ gW3pad,
                                  float* __restrict__ b1cat, float* __restrict__ b2cat) {
  int t = blockIdx.x * 256 + threadIdx.x;  // covers 4096 + 4608 + 2304 = 11008
  if (t < 4096) {
    int e = t >> 8, k = t & 255;
    gW3pad[e * 256 + k] = (e < 8) ? f2bf(gW3[k * 8 + e]) : (short)0;
  } else if (t < 4096 + 4608) {
    int u = t - 4096;
    b1cat[u] = u < 512 ? gb1[u] : eb1[u - 512];
  } else if (t < 4096 + 4608 + 2304) {
    int u = t - 4096 - 4608;
    b2cat[u] = u < 256 ? gb2[u] : eb2[u - 256];
  }
}

// ---------------- transpose + cast: [Z][R][C] f32 -> [Z][C][R] bf16 ----------------
__global__ void transpose_cast_kernel(const float* __restrict__ in, short* __restrict__ out,
                                      int R, int C) {
  __shared__ short tile[32][33];
  in += (size_t)blockIdx.z * R * C;
  out += (size_t)blockIdx.z * R * C;
  int c0 = blockIdx.x * 32, r0 = blockIdx.y * 32;
  int tx = threadIdx.x, ty = threadIdx.y;
#pragma unroll
  for (int i = 0; i < 4; ++i) {
    int r = r0 + ty + i * 8, c = c0 + tx;
    if (r < R && c < C) tile[ty + i * 8][tx] = f2bf(in[(size_t)r * C + c]);
  }
  __syncthreads();
#pragma unroll
  for (int i = 0; i < 4; ++i) {
    int c = c0 + ty + i * 8, r = r0 + tx;
    if (c < C && r < R) out[(size_t)c * R + r] = tile[tx][ty + i * 8];
  }
}

// two-source variant: z==0 reads gsrc, z>0 reads esrc[z-1]; dst contiguous by z
__global__ void transpose_cast2_kernel(const float* __restrict__ gsrc,
                                       const float* __restrict__ esrc,
                                       short* __restrict__ out, int R, int C) {
  __shared__ short tile[32][33];
  const float* in = (blockIdx.z == 0) ? gsrc : esrc + (size_t)(blockIdx.z - 1) * R * C;
  out += (size_t)blockIdx.z * R * C;
  int c0 = blockIdx.x * 32, r0 = blockIdx.y * 32;
  int tx = threadIdx.x, ty = threadIdx.y;
#pragma unroll
  for (int i = 0; i < 4; ++i) {
    int r = r0 + ty + i * 8, c = c0 + tx;
    if (r < R && c < C) tile[ty + i * 8][tx] = f2bf(in[(size_t)r * C + c]);
  }
  __syncthreads();
#pragma unroll
  for (int i = 0; i < 4; ++i) {
    int c = c0 + ty + i * 8, r = r0 + tx;
    if (c < C && r < R) out[(size_t)c * R + r] = tile[tx][ty + i * 8];
  }
}

#define BARRIER() asm volatile("s_barrier" ::: "memory")

// ---------------- BK=64 staging (L2L3 kernel): one operand half-tile ----------------
template <int ROWS>
DEVI void stage_half8(const short* __restrict__ g, int ld, int row0, int kt, int h,
                      short* ldsop, int wave, int lane) {
  constexpr int CPW = ROWS / 128;
  const int r_in = lane >> 3, c = lane & 7;
#pragma unroll
  for (int i = 0; i < CPW; ++i) {
    const int ch = h * (ROWS / 16) + wave * CPW + i;
    const int r = ch * 8 + r_in;
    const int cs = c ^ (r & 7);
    const short* src = g + (size_t)(row0 + r) * ld + kt * 64 + cs * 8;
    __builtin_amdgcn_global_load_lds((__attribute__((address_space(1))) void*)src,
                                     (__attribute__((address_space(3))) void*)(ldsop + ch * 512),
                                     16, 0, 0);
  }
}

// ---------------- BK=32 staging (L1 kernel): one 256-row operand half-tile ----------------
// LDS chunk = 16 rows x 32 shorts (1KB): lane>>2 = row-in-chunk, lane&3 = 16B slot.
// Slot c of row r holds global k-chunk c ^ ((r>>1)&3)  (conflict-free: 16 reading lanes
// spread 2-per-slot across all 32 banks; row stride 64B alternates bank halves by r&1).
DEVI void stage32(const short* __restrict__ g, int ld, int row0, int kt, int h,
                  short* ldsop, int wave, int lane) {
  const int ch = h * 8 + wave;
  const int r_in = lane >> 2, c = lane & 3;
  const int cs = c ^ ((r_in >> 1) & 3);
  const short* src = g + (size_t)(row0 + ch * 16 + r_in) * ld + kt * 32 + cs * 8;
  __builtin_amdgcn_global_load_lds((__attribute__((address_space(1))) void*)src,
                                   (__attribute__((address_space(3))) void*)(ldsop + ch * 512),
                                   16, 0, 0);
}

// ---------------- 8-phase 256x256 grouped GEMM, BK=32, 64KB LDS -> 2 blocks/CU ----------------
// Schedule isomorphic to the verified BK=64 structure (same phase/hazard ledger, scaled):
// p1:(kt+1,A,h1)  p2:(kt+1,B,h1)  p3:(kt+2,B,h0)  p4:(kt+2,A,h0); 1 staging instr per half
// -> prologue & boundary vmcnt(2). A-h0 last read p3, B-h0 last read p2 (same as BK=64).
template <int BM, int BN>
__global__ __launch_bounds__(512) void gemm8p_kernel(
    const short* __restrict__ A, const short* __restrict__ Bt,
    const float* __restrict__ bias, short* __restrict__ Cout,
    int K, int lda, int ldc, long AzOff, long BzOff, long CzOff, int BiasZOff,
    int nx, int nz) {
  constexpr int WN = BN / 4;          // 64
  constexpr int NF = WN / 16;         // 4
  constexpr int NH = NF / 2;          // 2
  constexpr int DB = (BM + BN) * 32;  // shorts per double-buffer (16384)
  extern __shared__ __align__(16) short smem[];
  const int bid = blockIdx.x;
  const int spx = gridDim.x >> 3;
  const int lin = (bid & 7) * spx + (bid >> 3);
  const int nxz = nx * nz;
  const int by = lin / nxz, rem = lin % nxz;
  const int bz = rem / nx, bx = rem % nx;
  A += (size_t)bz * AzOff;
  Bt += (size_t)bz * BzOff;
  Cout += (size_t)bz * CzOff;
  bias += bz * BiasZOff;
  const int tid = threadIdx.x, wave = tid >> 6, lane = tid & 63;
  const int l15 = lane & 15, l4 = lane >> 4;
  const int wm = wave >> 2, wn = wave & 3;
  const int brow = by * BM, bcol = bx * BN;
  const int NT = K / 32;

  auto FR = [&](const short* base, int r, int kc) {
    return *(const shortx8*)(base + r * 32 + ((kc ^ ((r >> 1) & 3)) << 3));
  };

  floatx4 acc[8][NF] = {};
  shortx8 af[4], bq[NF];

  // ---- prologue: tile0 (4 halves) + tile1 h0s; retire tile0, keep tile1 h0s in flight
  {
    short* a0 = smem;            short* b0 = smem + BM * 32;
    short* a1 = smem + DB;       short* b1 = smem + DB + BM * 32;
    stage32(A, lda, brow, 0, 0, a0, wave, lane);
    stage32(A, lda, brow, 0, 1, a0, wave, lane);
    stage32(Bt, K, bcol, 0, 0, b0, wave, lane);
    stage32(Bt, K, bcol, 0, 1, b0, wave, lane);
    stage32(Bt, K, bcol, 1, 0, b1, wave, lane);
    stage32(A, lda, brow, 1, 0, a1, wave, lane);
    asm volatile("s_waitcnt vmcnt(2)" ::: "memory");
    BARRIER();
  }

  for (int kt = 0; kt < NT; ++kt) {
    const int cur = kt & 1;
    const short* la = smem + cur * DB;
    const short* lb = la + BM * 32;
    short* an = smem + (cur ^ 1) * DB;       // +1-lead targets (next dbuf)
    short* bn = an + BM * 32;
    short* ac = smem + cur * DB;             // +2-lead targets (current dbuf)
    short* bc = ac + BM * 32;

    // ===== phase 1: read A m0-3 + B lo; stage (kt+1, A, h1) =====
#pragma unroll
    for (int m2 = 0; m2 < 4; ++m2) af[m2] = FR(la, wm * 128 + m2 * 16 + l15, l4);
#pragma unroll
    for (int n2 = 0; n2 < NH; ++n2) bq[n2] = FR(lb, wn * WN + n2 * 16 + l15, l4);
    if (kt + 1 < NT) stage32(A, lda, brow, kt + 1, 1, an, wave, lane);
    BARRIER();
    __builtin_amdgcn_s_setprio(1);
#pragma unroll
    for (int m2 = 0; m2 < 4; ++m2)
#pragma unroll
      for (int n2 = 0; n2 < NH; ++n2)
        acc[m2][n2] = __builtin_amdgcn_mfma_f32_16x16x32_bf16(af[m2], bq[n2], acc[m2][n2], 0, 0, 0);
    __builtin_amdgcn_s_setprio(0);
    BARRIER();

    // ===== phase 2: read B hi; stage (kt+1, B, h1) =====
#pragma unroll
    for (int n2 = 0; n2 < NH; ++n2) bq[NH + n2] = FR(lb, wn * WN + (NH + n2) * 16 + l15, l4);
    if (kt + 1 < NT) stage32(Bt, K, bcol, kt + 1, 1, bn, wave, lane);
    BARRIER();
    __builtin_amdgcn_s_setprio(1);
#pragma unroll
    for (int m2 = 0; m2 < 4; ++m2)
#pragma unroll
      for (int n2 = 0; n2 < NH; ++n2)
        acc[m2][NH + n2] =
            __builtin_amdgcn_mfma_f32_16x16x32_bf16(af[m2], bq[NH + n2], acc[m2][NH + n2], 0, 0, 0);
    __builtin_amdgcn_s_setprio(0);
    BARRIER();

    // ===== phase 3: read A m4-7; stage (kt+2, B, h0) =====
#pragma unroll
    for (int m2 = 0; m2 < 4; ++m2) af[m2] = FR(la, wm * 128 + (4 + m2) * 16 + l15, l4);
    if (kt + 2 < NT) stage32(Bt, K, bcol, kt + 2, 0, bc, wave, lane);
    BARRIER();
    __builtin_amdgcn_s_setprio(1);
#pragma unroll
    for (int m2 = 0; m2 < 4; ++m2)
#pragma unroll
      for (int n2 = 0; n2 < NH; ++n2)
        acc[4 + m2][n2] =
            __builtin_amdgcn_mfma_f32_16x16x32_bf16(af[m2], bq[n2], acc[4 + m2][n2], 0, 0, 0);
    __builtin_amdgcn_s_setprio(0);
    BARRIER();

    // ===== phase 4: stage (kt+2, A, h0); boundary counted-vmcnt =====
    if (kt + 2 < NT) stage32(A, lda, brow, kt + 2, 0, ac, wave, lane);
    BARRIER();
    __builtin_amdgcn_s_setprio(1);
#pragma unroll
    for (int m2 = 0; m2 < 4; ++m2)
#pragma unroll
      for (int n2 = 0; n2 < NH; ++n2)
        acc[4 + m2][NH + n2] = __builtin_amdgcn_mfma_f32_16x16x32_bf16(
            af[m2], bq[NH + n2], acc[4 + m2][NH + n2], 0, 0, 0);
    __builtin_amdgcn_s_setprio(0);
    if (kt + 1 < NT) {
      if (kt == NT - 2) asm volatile("s_waitcnt vmcnt(0)" ::: "memory");
      else              asm volatile("s_waitcnt vmcnt(2)" ::: "memory");
      BARRIER();
    }
  }

  // epilogue: scalar ELU + bf16 stores (r12/r15-verified; r14 proved LDS repack loses)
#pragma unroll
  for (int m2 = 0; m2 < 8; ++m2) {
    const int row0 = brow + wm * 128 + m2 * 16 + l4 * 4;
#pragma unroll
    for (int n2 = 0; n2 < NF; ++n2) {
      const int col = bcol + wn * WN + n2 * 16 + l15;
      const float bv = bias[col];
#pragma unroll
      for (int r = 0; r < 4; ++r) {
        float v = acc[m2][n2][r] + bv;
        v = v > 0.f ? v : (__expf(v) - 1.f);  // ELU
        Cout[(size_t)(row0 + r) * ldc + col] = f2bf(v);
      }
    }
  }
}

// ---------------- fused layer-2 + layer-3 + gate3 kernel (BM=256, BN=256, K=512, BK=64) ----------------
__global__ __launch_bounds__(512) void gemm8p_l2l3_kernel(
    const short* __restrict__ A, const short* __restrict__ Bt,
    const float* __restrict__ bias,
    const short* __restrict__ w3, const float* __restrict__ b3,
    const short* __restrict__ gw3pad, const float* __restrict__ gb3,
    float* __restrict__ elat, float* __restrict__ outW,
    int gBase, int nz, int lda) {
  constexpr int BM = 256, BN = 256, KT = 512;
  constexpr int NH = 2, DB = (BM + BN) * 64, NT = KT / 64;
  extern __shared__ __align__(16) short smem[];
  const int bid = blockIdx.x;
  const int spx = gridDim.x >> 3;
  const int lin = (bid & 7) * spx + (bid >> 3);
  const int by = lin / nz, bz = lin % nz;   // z-innermost on each XCD
  A += (size_t)bz * 512;                    // buf1 column offset
  Bt += (size_t)bz * 256 * 512;
  bias += bz * 256;
  const int tid = threadIdx.x, wave = tid >> 6, lane = tid & 63;
  const int l15 = lane & 15, l4 = lane >> 4;
  const int wm = wave >> 2, wn = wave & 3;
  const int brow = by * BM;

  auto FR = [&](const short* base, int r, int kc) {
    return *(const shortx8*)(base + r * 64 + ((kc ^ (r & 7)) << 3));
  };

  floatx4 acc[8][4] = {};
  shortx8 af[4][2], bq[4][2];

  {
    short* a0 = smem;            short* b0 = smem + BM * 64;
    short* a1 = smem + DB;       short* b1 = smem + DB + BM * 64;
    stage_half8<BM>(A, lda, brow, 0, 0, a0, wave, lane);
    stage_half8<BM>(A, lda, brow, 0, 1, a0, wave, lane);
    stage_half8<BN>(Bt, KT, 0, 0, 0, b0, wave, lane);
    stage_half8<BN>(Bt, KT, 0, 0, 1, b0, wave, lane);
    stage_half8<BN>(Bt, KT, 0, 1, 0, b1, wave, lane);
    stage_half8<BM>(A, lda, brow, 1, 0, a1, wave, lane);
    asm volatile("s_waitcnt vmcnt(4)" ::: "memory");
    BARRIER();
  }

  for (int kt = 0; kt < NT; ++kt) {
    const int cur = kt & 1;
    const short* la = smem + cur * DB;
    const short* lb = la + BM * 64;
    short* an = smem + (cur ^ 1) * DB;
    short* bn = an + BM * 64;
    short* ac = smem + cur * DB;
    short* bc = ac + BM * 64;

#pragma unroll
    for (int m2 = 0; m2 < 4; ++m2) {
      const int r = wm * 128 + m2 * 16 + l15;
#pragma unroll
      for (int ks = 0; ks < 2; ++ks) af[m2][ks] = FR(la, r, ks * 4 + l4);
    }
#pragma unroll
    for (int n2 = 0; n2 < NH; ++n2) {
      const int r = wn * 64 + n2 * 16 + l15;
#pragma unroll
      for (int ks = 0; ks < 2; ++ks) bq[n2][ks] = FR(lb, r, ks * 4 + l4);
    }
    if (kt + 1 < NT) stage_half8<BM>(A, lda, brow, kt + 1, 1, an, wave, lane);
    BARRIER();
    __builtin_amdgcn_s_setprio(1);
#pragma unroll
    for (int m2 = 0; m2 < 4; ++m2)
#pragma unroll
      for (int n2 = 0; n2 < NH; ++n2)
#pragma unroll
        for (int ks = 0; ks < 2; ++ks)
          acc[m2][n2] = __builtin_amdgcn_mfma_f32_16x16x32_bf16(af[m2][ks], bq[n2][ks],
                                                                acc[m2][n2], 0, 0, 0);
    __builtin_amdgcn_s_setprio(0);
    BARRIER();

#pragma unroll
    for (int n2 = 0; n2 < NH; ++n2) {
      const int r = wn * 64 + (NH + n2) * 16 + l15;
#pragma unroll
      for (int ks = 0; ks < 2; ++ks) bq[NH + n2][ks] = FR(lb, r, ks * 4 + l4);
    }
    if (kt + 1 < NT) stage_half8<BN>(Bt, KT, 0, kt + 1, 1, bn, wave, lane);
    BARRIER();
    __builtin_amdgcn_s_setprio(1);
#pragma unroll
    for (int m2 = 0; m2 < 4; ++m2)
#pragma unroll
      for (int n2 = 0; n2 < NH; ++n2)
#pragma unroll
        for (int ks = 0; ks < 2; ++ks)
          acc[m2][NH + n2] = __builtin_amdgcn_mfma_f32_16x16x32_bf16(af[m2][ks], bq[NH + n2][ks],
                                                                     acc[m2][NH + n2], 0, 0, 0);
    __builtin_amdgcn_s_setprio(0);
    BARRIER();

#pragma unroll
    for (int m2 = 0; m2 < 4; ++m2) {
      const int r = wm * 128 + (4 + m2) * 16 + l15;
#pragma unroll
      for (int ks = 0; ks < 2; ++ks) af[m2][ks] = FR(la, r, ks * 4 + l4);
    }
    if (kt + 2 < NT) stage_half8<BN>(Bt, KT, 0, kt + 2, 0, bc, wave, lane);
    BARRIER();
    __builtin_amdgcn_s_setprio(1);
#pragma unroll
    for (int m2 = 0; m2 < 4; ++m2)
#pragma unroll
      for (int n2 = 0; n2 < NH; ++n2)
#pragma unroll
        for (int ks = 0; ks < 2; ++ks)
          acc[4 + m2][n2] = __builtin_amdgcn_mfma_f32_16x16x32_bf16(af[m2][ks], bq[n2][ks],
                                                                    acc[4 + m2][n2], 0, 0, 0);
    __builtin_amdgcn_s_setprio(0);
    BARRIER();

    if (kt + 2 < NT) stage_half8<BM>(A, lda, brow, kt + 2, 0, ac, wave, lane);
    BARRIER();
    __builtin_amdgcn_s_setprio(1);
#pragma unroll
    for (int m2 = 0; m2 < 4; ++m2)
#pragma unroll
      for (int n2 = 0; n2 < NH; ++n2)
#pragma unroll
        for (int ks = 0; ks < 2; ++ks)
          acc[4 + m2][NH + n2] = __builtin_amdgcn_mfma_f32_16x16x32_bf16(
              af[m2][ks], bq[NH + n2][ks], acc[4 + m2][NH + n2], 0, 0, 0);
    __builtin_amdgcn_s_setprio(0);
    if (kt + 1 < NT) {
      if (kt == NT - 2) asm volatile("s_waitcnt vmcnt(0)" ::: "memory");
      else               asm volatile("s_waitcnt vmcnt(4)" ::: "memory");
      BARRIER();
    }
  }

  // ---- ELU -> bf16 X2 into LDS ([256][264] pad) — both paths ----
  constexpr int XS = 264;
  short* X = smem;
#pragma unroll
  for (int m2 = 0; m2 < 8; ++m2) {
    const int rw = wm * 128 + m2 * 16 + l4 * 4;
#pragma unroll
    for (int n2 = 0; n2 < 4; ++n2) {
      const int col = wn * 64 + n2 * 16 + l15;
      const float bv = bias[col];
#pragma unroll
      for (int r = 0; r < 4; ++r) {
        float v = acc[m2][n2][r] + bv;
        v = v > 0.f ? v : (__expf(v) - 1.f);
        X[(rw + r) * XS + col] = f2bf(v);
      }
    }
  }
  BARRIER();

  const int grp = gBase + bz;
  if (grp == 0) {
    // gating: logits = X2 @ gW3^T (+gb3), softmax over e=0..7  -> outW
    floatx4 lg[2] = {};
#pragma unroll
    for (int ks = 0; ks < 8; ++ks) {
      const int kc = ks * 4 + l4;
      shortx8 xa[2];
#pragma unroll
      for (int mi = 0; mi < 2; ++mi) {
        const int rw = wave * 32 + mi * 16 + l15;
        xa[mi] = *(const shortx8*)(X + rw * XS + kc * 8);
      }
      shortx8 wb = *(const shortx8*)(gw3pad + l15 * 256 + kc * 8);
#pragma unroll
      for (int mi = 0; mi < 2; ++mi)
        lg[mi] = __builtin_amdgcn_mfma_f32_16x16x32_bf16(xa[mi], wb, lg[mi], 0, 0, 0);
    }
    const float bg = gb3[l15 & 7];
#pragma unroll
    for (int mi = 0; mi < 2; ++mi) {
#pragma unroll
      for (int r = 0; r < 4; ++r) {
        float lv = lg[mi][r] + bg;
        float m = lv;
#pragma unroll
        for (int off = 1; off < 8; off <<= 1) m = fmaxf(m, __shfl_xor(m, off));
        float p = __expf(lv - m);
        float s = p;
#pragma unroll
        for (int off = 1; off < 8; off <<= 1) s += __shfl_xor(s, off);
        if (l15 < 8) {
          const int row = brow + wave * 32 + mi * 16 + l4 * 4 + r;
          outW[(size_t)row * 8 + l15] = p / s;
        }
      }
    }
    return;
  }

  // expert: per-wave 32-row L3 GEMM (K=256)
  const int e = grp - 1;
  const short* w3e = w3 + (size_t)e * 32 * 256;
  floatx4 a2[2][2] = {};
#pragma unroll
  for (int ks = 0; ks < 8; ++ks) {
    const int kc = ks * 4 + l4;
    shortx8 xa[2], wb[2];
#pragma unroll
    for (int mi = 0; mi < 2; ++mi) {
      const int rw = wave * 32 + mi * 16 + l15;
      xa[mi] = *(const shortx8*)(X + rw * XS + kc * 8);
    }
#pragma unroll
    for (int ni = 0; ni < 2; ++ni)
      wb[ni] = *(const shortx8*)(w3e + (ni * 16 + l15) * 256 + kc * 8);
#pragma unroll
    for (int mi = 0; mi < 2; ++mi)
#pragma unroll
      for (int ni = 0; ni < 2; ++ni)
        a2[mi][ni] = __builtin_amdgcn_mfma_f32_16x16x32_bf16(xa[mi], wb[ni], a2[mi][ni], 0, 0, 0);
  }
#pragma unroll
  for (int mi = 0; mi < 2; ++mi) {
#pragma unroll
    for (int ni = 0; ni < 2; ++ni) {
      const int col = ni * 16 + l15;
      const float bv = b3[e * 32 + col];
#pragma unroll
      for (int r = 0; r < 4; ++r) {
        const int row = brow + wave * 32 + mi * 16 + l4 * 4 + r;
        elat[(size_t)row * 256 + e * 32 + col] = a2[mi][ni][r] + bv;
      }
    }
  }
}

// ---------------- gated combine + L2 normalize: thread = (b,l) ----------------
__global__ void combine_norm_kernel(const float* __restrict__ elat,
                                    const float* __restrict__ gate,
                                    float* __restrict__ out) {
  int t = blockIdx.x * 256 + threadIdx.x;
  int b = t >> 5, l = t & 31;
  const float* er = elat + (size_t)b * 256;
  const float* gr = gate + (size_t)b * 8;
  float v = 0.f;
#pragma unroll
  for (int e = 0; e < 8; ++e) v += gr[e] * er[e * 32 + l];
  float ss = v * v;
#pragma unroll
  for (int off = 1; off < 32; off <<= 1) ss += __shfl_xor(ss, off, 32);
  out[t] = v / fmaxf(sqrtf(ss), 1e-12f);
}

extern "C" void kernel_launch(void* const* d_in, const int* in_sizes, int n_in,
                              void* d_out, int out_size, void* d_ws, size_t ws_size,
                              hipStream_t stream) {
  // defensive input remap by element-count signature (identity under dict order)
  static const int kExp[14] = {16777216, 16777216, 2097152, 4096, 1048576, 2048, 65536, 256,
                               262144, 512, 131072, 256, 2048, 8};
  const void* in[14];
  bool identity = (n_in >= 14);
  if (identity)
    for (int i = 0; i < 14; ++i)
      if (in_sizes[i] != kExp[i]) { identity = false; break; }
  if (identity) {
    for (int i = 0; i < 14; ++i) in[i] = d_in[i];
  } else {
    bool used[64] = {};
    for (int i = 0; i < 14; ++i) {
      in[i] = d_in[i < n_in ? i : 0];
      for (int j = 0; j < n_in && j < 64; ++j)
        if (!used[j] && in_sizes[j] == kExp[i]) { in[i] = d_in[j]; used[j] = true; break; }
    }
  }
  const float* obs = (const float*)in[0];
  const float* eW1 = (const float*)in[2];
  const float* eb1 = (const float*)in[3];
  const float* eW2 = (const float*)in[4];
  const float* eb2 = (const float*)in[5];
  const float* eW3 = (const float*)in[6];
  const float* eb3 = (const float*)in[7];
  const float* gW1 = (const float*)in[8];
  const float* gb1 = (const float*)in[9];
  const float* gW2 = (const float*)in[10];
  const float* gb2 = (const float*)in[11];
  const float* gW3 = (const float*)in[12];
  const float* gb3 = (const float*)in[13];

  char* ws = (char*)d_ws;
  size_t off = 0;
  auto carve = [&](size_t bytes) {
    char* p = ws + off;
    off += (bytes + 255) & ~(size_t)255;
    return p;
  };
  // groups ordered [gating, e0..e7]; 2 batches {5,4}; total ws ~242 MB (< 256 MiB)
  short* obs_bf = (short*)carve((size_t)Bsz * Din * 2);
  short* w1cat = (short*)carve((size_t)4608 * 512 * 2);   // [g+8e out-rows][K=512]
  short* w2cat = (short*)carve((size_t)2304 * 512 * 2);
  short* eW3t = (short*)carve((size_t)NE * Lout * H2 * 2);
  short* gW3pad = (short*)carve((size_t)16 * H2 * 2);     // rows 0-7 = gW3^T; 8-15 zero
  float* b1cat = (float*)carve(4608 * 4);
  float* b2cat = (float*)carve(2304 * 4);
  float* elat = (float*)carve((size_t)Bsz * 256 * 4);     // [B][E*32] f32
  short* buf1 = (short*)carve((size_t)Bsz * 2560 * 2);    // [B][5*512] (batch max)

  float* out_lat = (float*)d_out;                      // [B][32] f32
  float* out_w = (float*)d_out + (size_t)Bsz * Lout;   // [B][8]  f32

  constexpr int kLds1 = 2 * (256 + 256) * 32 * 2;  // 64 KiB -> 2 blocks/CU
  constexpr int kLdsF = 256 * 264 * 2;             // 132 KiB
  (void)hipFuncSetAttribute((const void*)gemm8p_kernel<256, 256>,
                            hipFuncAttributeMaxDynamicSharedMemorySize, kLds1);
  (void)hipFuncSetAttribute((const void*)gemm8p_l2l3_kernel,
                            hipFuncAttributeMaxDynamicSharedMemorySize, kLdsF);

  // prep: cast + merged transposes + small prep (5 launches)
  cast_bf16_kernel<<<2048, 256, 0, stream>>>(obs, obs_bf, Bsz * Din / 4);
  dim3 tb(32, 8);
  transpose_cast2_kernel<<<dim3(16, 16, 9), tb, 0, stream>>>(gW1, eW1, w1cat, Din, H1);
  transpose_cast2_kernel<<<dim3(8, 16, 9), tb, 0, stream>>>(gW2, eW2, w2cat, H1, H2);
  transpose_cast_kernel<<<dim3(1, 8, 8), tb, 0, stream>>>(eW3, eW3t, H2, Lout);
  prep_small_kernel<<<43, 256, 0, stream>>>(gW3, gb1, eb1, gb2, eb2, gW3pad, b1cat, b2cat);

  // batch 0: groups {g, e0..e3} (nz=5); batch 1: {e4..e7} (nz=4)
  gemm8p_kernel<256, 256><<<1280, 512, kLds1, stream>>>(
      obs_bf, w1cat, b1cat, buf1,
      512, 512, 2560, 0L, 512L * 512, 512L, 512, 2, 5);
  gemm8p_l2l3_kernel<<<640, 512, kLdsF, stream>>>(
      buf1, w2cat, b2cat, eW3t, eb3, gW3pad, gb3, elat, out_w, 0, 5, 2560);

  gemm8p_kernel<256, 256><<<1024, 512, kLds1, stream>>>(
      obs_bf, w1cat + (size_t)5 * 512 * 512, b1cat + 2560, buf1,
      512, 512, 2048, 0L, 512L * 512, 512L, 512, 2, 4);
  gemm8p_l2l3_kernel<<<512, 512, kLdsF, stream>>>(
      buf1, w2cat + (size_t)5 * 256 * 512, b2cat + 1280, eW3t, eb3, gW3pad, gb3,
      elat, out_w, 5, 4, 2048);

  combine_norm_kernel<<<(Bsz * Lout) / 256, 256, 0, stream>>>(elat, out_w, out_lat);
}

// Round 17
// 338.053 us; speedup vs baseline: 1.0356x; 1.0356x over previous
//
#include <hip/hip_runtime.h>
#include <hip/hip_bf16.h>

#define DEVI __device__ __forceinline__

typedef __attribute__((ext_vector_type(8))) short shortx8;
typedef __attribute__((ext_vector_type(4))) float floatx4;

static constexpr int Bsz = 32768, Din = 512, H1 = 512, H2 = 256, NE = 8, Lout = 32;

DEVI float bf2f(short s) {
  union { unsigned u; float f; } c;
  c.u = ((unsigned)(unsigned short)s) << 16;
  return c.f;
}
// round-to-nearest-even f32 -> bf16 (finite inputs only)
DEVI short f2bf(float f) {
  union { float f; unsigned u; } c; c.f = f;
  unsigned u = c.u + (0x7FFFu + ((c.u >> 16) & 1u));
  return (short)(u >> 16);
}

// ---------------- elementwise cast f32 -> bf16 ----------------
__global__ void cast_bf16_kernel(const float* __restrict__ in, short* __restrict__ out, int n4) {
  int stride = gridDim.x * blockDim.x;
  for (int i = blockIdx.x * blockDim.x + threadIdx.x; i < n4; i += stride) {
    float4 v = ((const float4*)in)[i];
    short4 o;
    o.x = f2bf(v.x); o.y = f2bf(v.y); o.z = f2bf(v.z); o.w = f2bf(v.w);
    ((short4*)out)[i] = o;
  }
}

// ---------------- small prep: gW3pad (16 rows, 8 real + 8 zero) + bias concats ----------------
__global__ void prep_small_kernel(const float* __restrict__ gW3,
                                  const float* __restrict__ gb1, const float* __restrict__ eb1,
                                  const float* __restrict__ gb2, const float* __restrict__ eb2,
                                  short* __restrict__ gW3pad,
                                  float* __restrict__ b1cat, float* __restrict__ b2cat) {
  int t = blockIdx.x * 256 + threadIdx.x;  // covers 4096 + 4608 + 2304 = 11008
  if (t < 4096) {
    int e = t >> 8, k = t & 255;
    gW3pad[e * 256 + k] = (e < 8) ? f2bf(gW3[k * 8 + e]) : (short)0;
  } else if (t < 4096 + 4608) {
    int u = t - 4096;
    b1cat[u] = u < 512 ? gb1[u] : eb1[u - 512];
  } else if (t < 4096 + 4608 + 2304) {
    int u = t - 4096 - 4608;
    b2cat[u] = u < 256 ? gb2[u] : eb2[u - 256];
  }
}

// ---------------- transpose + cast: [Z][R][C] f32 -> [Z][C][R] bf16 ----------------
__global__ void transpose_cast_kernel(const float* __restrict__ in, short* __restrict__ out,
                                      int R, int C) {
  __shared__ short tile[32][33];
  in += (size_t)blockIdx.z * R * C;
  out += (size_t)blockIdx.z * R * C;
  int c0 = blockIdx.x * 32, r0 = blockIdx.y * 32;
  int tx = threadIdx.x, ty = threadIdx.y;
#pragma unroll
  for (int i = 0; i < 4; ++i) {
    int r = r0 + ty + i * 8, c = c0 + tx;
    if (r < R && c < C) tile[ty + i * 8][tx] = f2bf(in[(size_t)r * C + c]);
  }
  __syncthreads();
#pragma unroll
  for (int i = 0; i < 4; ++i) {
    int c = c0 + ty + i * 8, r = r0 + tx;
    if (c < C && r < R) out[(size_t)c * R + r] = tile[tx][ty + i * 8];
  }
}

// two-source variant: z==0 reads gsrc, z>0 reads esrc[z-1]; dst contiguous by z
__global__ void transpose_cast2_kernel(const float* __restrict__ gsrc,
                                       const float* __restrict__ esrc,
                                       short* __restrict__ out, int R, int C) {
  __shared__ short tile[32][33];
  const float* in = (blockIdx.z == 0) ? gsrc : esrc + (size_t)(blockIdx.z - 1) * R * C;
  out += (size_t)blockIdx.z * R * C;
  int c0 = blockIdx.x * 32, r0 = blockIdx.y * 32;
  int tx = threadIdx.x, ty = threadIdx.y;
#pragma unroll
  for (int i = 0; i < 4; ++i) {
    int r = r0 + ty + i * 8, c = c0 + tx;
    if (r < R && c < C) tile[ty + i * 8][tx] = f2bf(in[(size_t)r * C + c]);
  }
  __syncthreads();
#pragma unroll
  for (int i = 0; i < 4; ++i) {
    int c = c0 + ty + i * 8, r = r0 + tx;
    if (c < C && r < R) out[(size_t)c * R + r] = tile[tx][ty + i * 8];
  }
}

#define BARRIER() asm volatile("s_barrier" ::: "memory")

// ---------------- 8-phase staging: one operand half-tile ----------------
template <int ROWS>
DEVI void stage_half8(const short* __restrict__ g, int ld, int row0, int kt, int h,
                      short* ldsop, int wave, int lane) {
  constexpr int CPW = ROWS / 128;
  const int r_in = lane >> 3, c = lane & 7;
#pragma unroll
  for (int i = 0; i < CPW; ++i) {
    const int ch = h * (ROWS / 16) + wave * CPW + i;
    const int r = ch * 8 + r_in;
    const int cs = c ^ (r & 7);
    const short* src = g + (size_t)(row0 + r) * ld + kt * 64 + cs * 8;
    __builtin_amdgcn_global_load_lds((__attribute__((address_space(1))) void*)src,
                                     (__attribute__((address_space(3))) void*)(ldsop + ch * 512),
                                     16, 0, 0);
  }
}

// ---------------- 8-phase 256xBN grouped GEMM (layer-1; verified r8/r10/r12/r15 structure) ----------------
template <int BM, int BN>
__global__ __launch_bounds__(512) void gemm8p_kernel(
    const short* __restrict__ A, const short* __restrict__ Bt,
    const float* __restrict__ bias, short* __restrict__ Cout,
    int K, int lda, int ldc, long AzOff, long BzOff, long CzOff, int BiasZOff,
    int nx, int nz) {
  constexpr int WN = BN / 4;
  constexpr int NF = WN / 16;
  constexpr int NH = NF / 2;
  constexpr int DB = (BM + BN) * 64;
  extern __shared__ __align__(16) short smem[];
  const int bid = blockIdx.x;
  const int spx = gridDim.x >> 3;
  const int lin = (bid & 7) * spx + (bid >> 3);
  const int nxz = nx * nz;
  const int by = lin / nxz, rem = lin % nxz;
  const int bz = rem / nx, bx = rem % nx;
  A += (size_t)bz * AzOff;
  Bt += (size_t)bz * BzOff;
  Cout += (size_t)bz * CzOff;
  bias += bz * BiasZOff;
  const int tid = threadIdx.x, wave = tid >> 6, lane = tid & 63;
  const int l15 = lane & 15, l4 = lane >> 4;
  const int wm = wave >> 2, wn = wave & 3;
  const int brow = by * BM, bcol = bx * BN;
  const int NT = K / 64;

  auto FR = [&](const short* base, int r, int kc) {
    return *(const shortx8*)(base + r * 64 + ((kc ^ (r & 7)) << 3));
  };

  floatx4 acc[8][NF] = {};
  shortx8 af[4][2], bq[NF][2];

  {
    short* a0 = smem;            short* b0 = smem + BM * 64;
    short* a1 = smem + DB;       short* b1 = smem + DB + BM * 64;
    stage_half8<BM>(A, lda, brow, 0, 0, a0, wave, lane);
    stage_half8<BM>(A, lda, brow, 0, 1, a0, wave, lane);
    stage_half8<BN>(Bt, K, bcol, 0, 0, b0, wave, lane);
    stage_half8<BN>(Bt, K, bcol, 0, 1, b0, wave, lane);
    if (NT > 1) {
      stage_half8<BN>(Bt, K, bcol, 1, 0, b1, wave, lane);
      stage_half8<BM>(A, lda, brow, 1, 0, a1, wave, lane);
      if constexpr (BN == 256) asm volatile("s_waitcnt vmcnt(4)" ::: "memory");
      else                     asm volatile("s_waitcnt vmcnt(3)" ::: "memory");
    } else {
      asm volatile("s_waitcnt vmcnt(0)" ::: "memory");
    }
    BARRIER();
  }

  for (int kt = 0; kt < NT; ++kt) {
    const int cur = kt & 1;
    const short* la = smem + cur * DB;
    const short* lb = la + BM * 64;
    short* an = smem + (cur ^ 1) * DB;
    short* bn = an + BM * 64;
    short* ac = smem + cur * DB;
    short* bc = ac + BM * 64;

#pragma unroll
    for (int m2 = 0; m2 < 4; ++m2) {
      const int r = wm * 128 + m2 * 16 + l15;
#pragma unroll
      for (int ks = 0; ks < 2; ++ks) af[m2][ks] = FR(la, r, ks * 4 + l4);
    }
#pragma unroll
    for (int n2 = 0; n2 < NH; ++n2) {
      const int r = wn * WN + n2 * 16 + l15;
#pragma unroll
      for (int ks = 0; ks < 2; ++ks) bq[n2][ks] = FR(lb, r, ks * 4 + l4);
    }
    if (kt + 1 < NT) stage_half8<BM>(A, lda, brow, kt + 1, 1, an, wave, lane);
    BARRIER();
    __builtin_amdgcn_s_setprio(1);
#pragma unroll
    for (int m2 = 0; m2 < 4; ++m2)
#pragma unroll
      for (int n2 = 0; n2 < NH; ++n2)
#pragma unroll
        for (int ks = 0; ks < 2; ++ks)
          acc[m2][n2] = __builtin_amdgcn_mfma_f32_16x16x32_bf16(af[m2][ks], bq[n2][ks],
                                                                acc[m2][n2], 0, 0, 0);
    __builtin_amdgcn_s_setprio(0);
    BARRIER();

#pragma unroll
    for (int n2 = 0; n2 < NH; ++n2) {
      const int r = wn * WN + (NH + n2) * 16 + l15;
#pragma unroll
      for (int ks = 0; ks < 2; ++ks) bq[NH + n2][ks] = FR(lb, r, ks * 4 + l4);
    }
    if (kt + 1 < NT) stage_half8<BN>(Bt, K, bcol, kt + 1, 1, bn, wave, lane);
    BARRIER();
    __builtin_amdgcn_s_setprio(1);
#pragma unroll
    for (int m2 = 0; m2 < 4; ++m2)
#pragma unroll
      for (int n2 = 0; n2 < NH; ++n2)
#pragma unroll
        for (int ks = 0; ks < 2; ++ks)
          acc[m2][NH + n2] = __builtin_amdgcn_mfma_f32_16x16x32_bf16(af[m2][ks], bq[NH + n2][ks],
                                                                     acc[m2][NH + n2], 0, 0, 0);
    __builtin_amdgcn_s_setprio(0);
    BARRIER();

#pragma unroll
    for (int m2 = 0; m2 < 4; ++m2) {
      const int r = wm * 128 + (4 + m2) * 16 + l15;
#pragma unroll
      for (int ks = 0; ks < 2; ++ks) af[m2][ks] = FR(la, r, ks * 4 + l4);
    }
    if (kt + 2 < NT) stage_half8<BN>(Bt, K, bcol, kt + 2, 0, bc, wave, lane);
    BARRIER();
    __builtin_amdgcn_s_setprio(1);
#pragma unroll
    for (int m2 = 0; m2 < 4; ++m2)
#pragma unroll
      for (int n2 = 0; n2 < NH; ++n2)
#pragma unroll
        for (int ks = 0; ks < 2; ++ks)
          acc[4 + m2][n2] = __builtin_amdgcn_mfma_f32_16x16x32_bf16(af[m2][ks], bq[n2][ks],
                                                                    acc[4 + m2][n2], 0, 0, 0);
    __builtin_amdgcn_s_setprio(0);
    BARRIER();

    if (kt + 2 < NT) stage_half8<BM>(A, lda, brow, kt + 2, 0, ac, wave, lane);
    BARRIER();
    __builtin_amdgcn_s_setprio(1);
#pragma unroll
    for (int m2 = 0; m2 < 4; ++m2)
#pragma unroll
      for (int n2 = 0; n2 < NH; ++n2)
#pragma unroll
        for (int ks = 0; ks < 2; ++ks)
          acc[4 + m2][NH + n2] = __builtin_amdgcn_mfma_f32_16x16x32_bf16(
              af[m2][ks], bq[NH + n2][ks], acc[4 + m2][NH + n2], 0, 0, 0);
    __builtin_amdgcn_s_setprio(0);
    if (kt + 1 < NT) {
      if (kt == NT - 2) {
        asm volatile("s_waitcnt vmcnt(0)" ::: "memory");
      } else {
        if constexpr (BN == 256) asm volatile("s_waitcnt vmcnt(4)" ::: "memory");
        else                     asm volatile("s_waitcnt vmcnt(3)" ::: "memory");
      }
      BARRIER();
    }
  }

  // epilogue: scalar ELU + bf16 stores (r12/r15-verified; stores are fire-and-forget,
  // r14 proved an LDS repack here costs more than it saves — bank conflicts)
#pragma unroll
  for (int m2 = 0; m2 < 8; ++m2) {
    const int row0 = brow + wm * 128 + m2 * 16 + l4 * 4;
#pragma unroll
    for (int n2 = 0; n2 < NF; ++n2) {
      const int col = bcol + wn * WN + n2 * 16 + l15;
      const float bv = bias[col];
#pragma unroll
      for (int r = 0; r < 4; ++r) {
        float v = acc[m2][n2][r] + bv;
        v = v > 0.f ? v : (__expf(v) - 1.f);  // ELU
        Cout[(size_t)(row0 + r) * ldc + col] = f2bf(v);
      }
    }
  }
}

// ---------------- fused layer-2 + layer-3 + gate3 kernel (BM=256, BN=256, K=512) ----------------
__global__ __launch_bounds__(512) void gemm8p_l2l3_kernel(
    const short* __restrict__ A, const short* __restrict__ Bt,
    const float* __restrict__ bias,
    const short* __restrict__ w3, const float* __restrict__ b3,
    const short* __restrict__ gw3pad, const float* __restrict__ gb3,
    float* __restrict__ elat, float* __restrict__ outW,
    int gBase, int nz, int lda) {
  constexpr int BM = 256, BN = 256, KT = 512;
  constexpr int NH = 2, DB = (BM + BN) * 64, NT = KT / 64;
  extern __shared__ __align__(16) short smem[];
  const int bid = blockIdx.x;
  const int spx = gridDim.x >> 3;
  const int lin = (bid & 7) * spx + (bid >> 3);
  const int by = lin / nz, bz = lin % nz;   // z-innermost on each XCD
  A += (size_t)bz * 512;                    // buf1 column offset
  Bt += (size_t)bz * 256 * 512;
  bias += bz * 256;
  const int tid = threadIdx.x, wave = tid >> 6, lane = tid & 63;
  const int l15 = lane & 15, l4 = lane >> 4;
  const int wm = wave >> 2, wn = wave & 3;
  const int brow = by * BM;

  auto FR = [&](const short* base, int r, int kc) {
    return *(const shortx8*)(base + r * 64 + ((kc ^ (r & 7)) << 3));
  };

  floatx4 acc[8][4] = {};
  shortx8 af[4][2], bq[4][2];

  {
    short* a0 = smem;            short* b0 = smem + BM * 64;
    short* a1 = smem + DB;       short* b1 = smem + DB + BM * 64;
    stage_half8<BM>(A, lda, brow, 0, 0, a0, wave, lane);
    stage_half8<BM>(A, lda, brow, 0, 1, a0, wave, lane);
    stage_half8<BN>(Bt, KT, 0, 0, 0, b0, wave, lane);
    stage_half8<BN>(Bt, KT, 0, 0, 1, b0, wave, lane);
    stage_half8<BN>(Bt, KT, 0, 1, 0, b1, wave, lane);
    stage_half8<BM>(A, lda, brow, 1, 0, a1, wave, lane);
    asm volatile("s_waitcnt vmcnt(4)" ::: "memory");
    BARRIER();
  }

  for (int kt = 0; kt < NT; ++kt) {
    const int cur = kt & 1;
    const short* la = smem + cur * DB;
    const short* lb = la + BM * 64;
    short* an = smem + (cur ^ 1) * DB;
    short* bn = an + BM * 64;
    short* ac = smem + cur * DB;
    short* bc = ac + BM * 64;

#pragma unroll
    for (int m2 = 0; m2 < 4; ++m2) {
      const int r = wm * 128 + m2 * 16 + l15;
#pragma unroll
      for (int ks = 0; ks < 2; ++ks) af[m2][ks] = FR(la, r, ks * 4 + l4);
    }
#pragma unroll
    for (int n2 = 0; n2 < NH; ++n2) {
      const int r = wn * 64 + n2 * 16 + l15;
#pragma unroll
      for (int ks = 0; ks < 2; ++ks) bq[n2][ks] = FR(lb, r, ks * 4 + l4);
    }
    if (kt + 1 < NT) stage_half8<BM>(A, lda, brow, kt + 1, 1, an, wave, lane);
    BARRIER();
    __builtin_amdgcn_s_setprio(1);
#pragma unroll
    for (int m2 = 0; m2 < 4; ++m2)
#pragma unroll
      for (int n2 = 0; n2 < NH; ++n2)
#pragma unroll
        for (int ks = 0; ks < 2; ++ks)
          acc[m2][n2] = __builtin_amdgcn_mfma_f32_16x16x32_bf16(af[m2][ks], bq[n2][ks],
                                                                acc[m2][n2], 0, 0, 0);
    __builtin_amdgcn_s_setprio(0);
    BARRIER();

#pragma unroll
    for (int n2 = 0; n2 < NH; ++n2) {
      const int r = wn * 64 + (NH + n2) * 16 + l15;
#pragma unroll
      for (int ks = 0; ks < 2; ++ks) bq[NH + n2][ks] = FR(lb, r, ks * 4 + l4);
    }
    if (kt + 1 < NT) stage_half8<BN>(Bt, KT, 0, kt + 1, 1, bn, wave, lane);
    BARRIER();
    __builtin_amdgcn_s_setprio(1);
#pragma unroll
    for (int m2 = 0; m2 < 4; ++m2)
#pragma unroll
      for (int n2 = 0; n2 < NH; ++n2)
#pragma unroll
        for (int ks = 0; ks < 2; ++ks)
          acc[m2][NH + n2] = __builtin_amdgcn_mfma_f32_16x16x32_bf16(af[m2][ks], bq[NH + n2][ks],
                                                                     acc[m2][NH + n2], 0, 0, 0);
    __builtin_amdgcn_s_setprio(0);
    BARRIER();

#pragma unroll
    for (int m2 = 0; m2 < 4; ++m2) {
      const int r = wm * 128 + (4 + m2) * 16 + l15;
#pragma unroll
      for (int ks = 0; ks < 2; ++ks) af[m2][ks] = FR(la, r, ks * 4 + l4);
    }
    if (kt + 2 < NT) stage_half8<BN>(Bt, KT, 0, kt + 2, 0, bc, wave, lane);
    BARRIER();
    __builtin_amdgcn_s_setprio(1);
#pragma unroll
    for (int m2 = 0; m2 < 4; ++m2)
#pragma unroll
      for (int n2 = 0; n2 < NH; ++n2)
#pragma unroll
        for (int ks = 0; ks < 2; ++ks)
          acc[4 + m2][n2] = __builtin_amdgcn_mfma_f32_16x16x32_bf16(af[m2][ks], bq[n2][ks],
                                                                    acc[4 + m2][n2], 0, 0, 0);
    __builtin_amdgcn_s_setprio(0);
    BARRIER();

    if (kt + 2 < NT) stage_half8<BM>(A, lda, brow, kt + 2, 0, ac, wave, lane);
    BARRIER();
    __builtin_amdgcn_s_setprio(1);
#pragma unroll
    for (int m2 = 0; m2 < 4; ++m2)
#pragma unroll
      for (int n2 = 0; n2 < NH; ++n2)
#pragma unroll
        for (int ks = 0; ks < 2; ++ks)
          acc[4 + m2][NH + n2] = __builtin_amdgcn_mfma_f32_16x16x32_bf16(
              af[m2][ks], bq[NH + n2][ks], acc[4 + m2][NH + n2], 0, 0, 0);
    __builtin_amdgcn_s_setprio(0);
    if (kt + 1 < NT) {
      if (kt == NT - 2) asm volatile("s_waitcnt vmcnt(0)" ::: "memory");
      else               asm volatile("s_waitcnt vmcnt(4)" ::: "memory");
      BARRIER();
    }
  }

  // ---- ELU -> bf16 X2 into LDS ([256][264] pad) — both paths ----
  constexpr int XS = 264;
  short* X = smem;
#pragma unroll
  for (int m2 = 0; m2 < 8; ++m2) {
    const int rw = wm * 128 + m2 * 16 + l4 * 4;
#pragma unroll
    for (int n2 = 0; n2 < 4; ++n2) {
      const int col = wn * 64 + n2 * 16 + l15;
      const float bv = bias[col];
#pragma unroll
      for (int r = 0; r < 4; ++r) {
        float v = acc[m2][n2][r] + bv;
        v = v > 0.f ? v : (__expf(v) - 1.f);
        X[(rw + r) * XS + col] = f2bf(v);
      }
    }
  }
  BARRIER();

  const int grp = gBase + bz;
  if (grp == 0) {
    // gating: logits = X2 @ gW3^T (+gb3), softmax over e=0..7  -> outW
    floatx4 lg[2] = {};
#pragma unroll
    for (int ks = 0; ks < 8; ++ks) {
      const int kc = ks * 4 + l4;
      shortx8 xa[2];
#pragma unroll
      for (int mi = 0; mi < 2; ++mi) {
        const int rw = wave * 32 + mi * 16 + l15;
        xa[mi] = *(const shortx8*)(X + rw * XS + kc * 8);
      }
      shortx8 wb = *(const shortx8*)(gw3pad + l15 * 256 + kc * 8);
#pragma unroll
      for (int mi = 0; mi < 2; ++mi)
        lg[mi] = __builtin_amdgcn_mfma_f32_16x16x32_bf16(xa[mi], wb, lg[mi], 0, 0, 0);
    }
    const float bg = gb3[l15 & 7];
#pragma unroll
    for (int mi = 0; mi < 2; ++mi) {
#pragma unroll
      for (int r = 0; r < 4; ++r) {
        float lv = lg[mi][r] + bg;
        float m = lv;
#pragma unroll
        for (int off = 1; off < 8; off <<= 1) m = fmaxf(m, __shfl_xor(m, off));
        float p = __expf(lv - m);
        float s = p;
#pragma unroll
        for (int off = 1; off < 8; off <<= 1) s += __shfl_xor(s, off);
        if (l15 < 8) {
          const int row = brow + wave * 32 + mi * 16 + l4 * 4 + r;
          outW[(size_t)row * 8 + l15] = p / s;
        }
      }
    }
    return;
  }

  // expert: per-wave 32-row L3 GEMM (K=256)
  const int e = grp - 1;
  const short* w3e = w3 + (size_t)e * 32 * 256;
  floatx4 a2[2][2] = {};
#pragma unroll
  for (int ks = 0; ks < 8; ++ks) {
    const int kc = ks * 4 + l4;
    shortx8 xa[2], wb[2];
#pragma unroll
    for (int mi = 0; mi < 2; ++mi) {
      const int rw = wave * 32 + mi * 16 + l15;
      xa[mi] = *(const shortx8*)(X + rw * XS + kc * 8);
    }
#pragma unroll
    for (int ni = 0; ni < 2; ++ni)
      wb[ni] = *(const shortx8*)(w3e + (ni * 16 + l15) * 256 + kc * 8);
#pragma unroll
    for (int mi = 0; mi < 2; ++mi)
#pragma unroll
      for (int ni = 0; ni < 2; ++ni)
        a2[mi][ni] = __builtin_amdgcn_mfma_f32_16x16x32_bf16(xa[mi], wb[ni], a2[mi][ni], 0, 0, 0);
  }
#pragma unroll
  for (int mi = 0; mi < 2; ++mi) {
#pragma unroll
    for (int ni = 0; ni < 2; ++ni) {
      const int col = ni * 16 + l15;
      const float bv = b3[e * 32 + col];
#pragma unroll
      for (int r = 0; r < 4; ++r) {
        const int row = brow + wave * 32 + mi * 16 + l4 * 4 + r;
        elat[(size_t)row * 256 + e * 32 + col] = a2[mi][ni][r] + bv;
      }
    }
  }
}

// ---------------- gated combine + L2 normalize: thread = (b,l) ----------------
__global__ void combine_norm_kernel(const float* __restrict__ elat,
                                    const float* __restrict__ gate,
                                    float* __restrict__ out) {
  int t = blockIdx.x * 256 + threadIdx.x;
  int b = t >> 5, l = t & 31;
  const float* er = elat + (size_t)b * 256;
  const float* gr = gate + (size_t)b * 8;
  float v = 0.f;
#pragma unroll
  for (int e = 0; e < 8; ++e) v += gr[e] * er[e * 32 + l];
  float ss = v * v;
#pragma unroll
  for (int off = 1; off < 32; off <<= 1) ss += __shfl_xor(ss, off, 32);
  out[t] = v / fmaxf(sqrtf(ss), 1e-12f);
}

extern "C" void kernel_launch(void* const* d_in, const int* in_sizes, int n_in,
                              void* d_out, int out_size, void* d_ws, size_t ws_size,
                              hipStream_t stream) {
  // defensive input remap by element-count signature (identity under dict order)
  static const int kExp[14] = {16777216, 16777216, 2097152, 4096, 1048576, 2048, 65536, 256,
                               262144, 512, 131072, 256, 2048, 8};
  const void* in[14];
  bool identity = (n_in >= 14);
  if (identity)
    for (int i = 0; i < 14; ++i)
      if (in_sizes[i] != kExp[i]) { identity = false; break; }
  if (identity) {
    for (int i = 0; i < 14; ++i) in[i] = d_in[i];
  } else {
    bool used[64] = {};
    for (int i = 0; i < 14; ++i) {
      in[i] = d_in[i < n_in ? i : 0];
      for (int j = 0; j < n_in && j < 64; ++j)
        if (!used[j] && in_sizes[j] == kExp[i]) { in[i] = d_in[j]; used[j] = true; break; }
    }
  }
  const float* obs = (const float*)in[0];
  const float* eW1 = (const float*)in[2];
  const float* eb1 = (const float*)in[3];
  const float* eW2 = (const float*)in[4];
  const float* eb2 = (const float*)in[5];
  const float* eW3 = (const float*)in[6];
  const float* eb3 = (const float*)in[7];
  const float* gW1 = (const float*)in[8];
  const float* gb1 = (const float*)in[9];
  const float* gW2 = (const float*)in[10];
  const float* gb2 = (const float*)in[11];
  const float* gW3 = (const float*)in[12];
  const float* gb3 = (const float*)in[13];

  char* ws = (char*)d_ws;
  size_t off = 0;
  auto carve = [&](size_t bytes) {
    char* p = ws + off;
    off += (bytes + 255) & ~(size_t)255;
    return p;
  };
  // groups ordered [gating, e0..e7]; 2 batches {5,4}; total ws ~242 MB (< 256 MiB)
  short* obs_bf = (short*)carve((size_t)Bsz * Din * 2);
  short* w1cat = (short*)carve((size_t)4608 * 512 * 2);   // [g+8e out-rows][K=512]
  short* w2cat = (short*)carve((size_t)2304 * 512 * 2);
  short* eW3t = (short*)carve((size_t)NE * Lout * H2 * 2);
  short* gW3pad = (short*)carve((size_t)16 * H2 * 2);     // rows 0-7 = gW3^T; 8-15 zero
  float* b1cat = (float*)carve(4608 * 4);
  float* b2cat = (float*)carve(2304 * 4);
  float* elat = (float*)carve((size_t)Bsz * 256 * 4);     // [B][E*32] f32
  short* buf1 = (short*)carve((size_t)Bsz * 2560 * 2);    // [B][5*512] (batch max)

  float* out_lat = (float*)d_out;                      // [B][32] f32
  float* out_w = (float*)d_out + (size_t)Bsz * Lout;   // [B][8]  f32

  constexpr int kLds1 = 2 * (256 + 256) * 64 * 2;  // 128 KiB
  constexpr int kLdsF = 256 * 264 * 2;             // 132 KiB
  (void)hipFuncSetAttribute((const void*)gemm8p_kernel<256, 256>,
                            hipFuncAttributeMaxDynamicSharedMemorySize, kLds1);
  (void)hipFuncSetAttribute((const void*)gemm8p_l2l3_kernel,
                            hipFuncAttributeMaxDynamicSharedMemorySize, kLdsF);

  // prep: cast + merged transposes + small prep (5 launches)
  cast_bf16_kernel<<<2048, 256, 0, stream>>>(obs, obs_bf, Bsz * Din / 4);
  dim3 tb(32, 8);
  transpose_cast2_kernel<<<dim3(16, 16, 9), tb, 0, stream>>>(gW1, eW1, w1cat, Din, H1);
  transpose_cast2_kernel<<<dim3(8, 16, 9), tb, 0, stream>>>(gW2, eW2, w2cat, H1, H2);
  transpose_cast_kernel<<<dim3(1, 8, 8), tb, 0, stream>>>(eW3, eW3t, H2, Lout);
  prep_small_kernel<<<43, 256, 0, stream>>>(gW3, gb1, eb1, gb2, eb2, gW3pad, b1cat, b2cat);

  // batch 0: groups {g, e0..e3} (nz=5); batch 1: {e4..e7} (nz=4)
  gemm8p_kernel<256, 256><<<1280, 512, kLds1, stream>>>(
      obs_bf, w1cat, b1cat, buf1,
      512, 512, 2560, 0L, 512L * 512, 512L, 512, 2, 5);
  gemm8p_l2l3_kernel<<<640, 512, kLdsF, stream>>>(
      buf1, w2cat, b2cat, eW3t, eb3, gW3pad, gb3, elat, out_w, 0, 5, 2560);

  gemm8p_kernel<256, 256><<<1024, 512, kLds1, stream>>>(
      obs_bf, w1cat + (size_t)5 * 512 * 512, b1cat + 2560, buf1,
      512, 512, 2048, 0L, 512L * 512, 512L, 512, 2, 4);
  gemm8p_l2l3_kernel<<<512, 512, kLdsF, stream>>>(
      buf1, w2cat + (size_t)5 * 256 * 512, b2cat + 1280, eW3t, eb3, gW3pad, gb3,
      elat, out_w, 5, 4, 2048);

  combine_norm_kernel<<<(Bsz * Lout) / 256, 256, 0, stream>>>(elat, out_w, out_lat);
}

// Round 18
// 329.285 us; speedup vs baseline: 1.0631x; 1.0266x over previous
//
#include <hip/hip_runtime.h>
#include <hip/hip_bf16.h>

#define DEVI __device__ __forceinline__

typedef __attribute__((ext_vector_type(8))) short shortx8;
typedef __attribute__((ext_vector_type(4))) float floatx4;

static constexpr int Bsz = 32768, Din = 512, H1 = 512, H2 = 256, NE = 8, Lout = 32;

DEVI float bf2f(short s) {
  union { unsigned u; float f; } c;
  c.u = ((unsigned)(unsigned short)s) << 16;
  return c.f;
}
// round-to-nearest-even f32 -> bf16 (finite inputs only)
DEVI short f2bf(float f) {
  union { float f; unsigned u; } c; c.f = f;
  unsigned u = c.u + (0x7FFFu + ((c.u >> 16) & 1u));
  return (short)(u >> 16);
}

// ---------------- elementwise cast f32 -> bf16 ----------------
__global__ void cast_bf16_kernel(const float* __restrict__ in, short* __restrict__ out, int n4) {
  int stride = gridDim.x * blockDim.x;
  for (int i = blockIdx.x * blockDim.x + threadIdx.x; i < n4; i += stride) {
    float4 v = ((const float4*)in)[i];
    short4 o;
    o.x = f2bf(v.x); o.y = f2bf(v.y); o.z = f2bf(v.z); o.w = f2bf(v.w);
    ((short4*)out)[i] = o;
  }
}

// ---------------- merged W1+W2 transpose: z<9 -> W1 piece, z>=9 -> W2 piece ----------------
// dst layout per group: [C][R] bf16 (B^T form for the GEMM)
__global__ void transpose_w12_kernel(const float* __restrict__ gW1, const float* __restrict__ eW1,
                                     const float* __restrict__ gW2, const float* __restrict__ eW2,
                                     short* __restrict__ w1cat, short* __restrict__ w2cat) {
  __shared__ short tile[32][33];
  const int z = blockIdx.z;
  const float* in;
  short* out;
  int R, C;
  if (z < 9) {
    R = 512; C = 512;
    in = z ? eW1 + (size_t)(z - 1) * 262144 : gW1;
    out = w1cat + (size_t)z * 262144;
  } else {
    R = 512; C = 256;
    if (blockIdx.x >= 8) return;  // uniform per-block, before any barrier
    const int zz = z - 9;
    in = zz ? eW2 + (size_t)(zz - 1) * 131072 : gW2;
    out = w2cat + (size_t)zz * 131072;
  }
  int c0 = blockIdx.x * 32, r0 = blockIdx.y * 32;
  int tx = threadIdx.x, ty = threadIdx.y;
#pragma unroll
  for (int i = 0; i < 4; ++i) {
    int r = r0 + ty + i * 8, c = c0 + tx;
    tile[ty + i * 8][tx] = f2bf(in[(size_t)r * C + c]);
  }
  __syncthreads();
#pragma unroll
  for (int i = 0; i < 4; ++i) {
    int c = c0 + ty + i * 8, r = r0 + tx;
    out[(size_t)c * R + r] = tile[tx][ty + i * 8];
  }
}

// ---------------- merged small prep: eW3t + gW3pad + bias concats (76544 threads) ----------------
__global__ void prep_all_kernel(const float* __restrict__ eW3, const float* __restrict__ gW3,
                                const float* __restrict__ gb1, const float* __restrict__ eb1,
                                const float* __restrict__ gb2, const float* __restrict__ eb2,
                                short* __restrict__ eW3t, short* __restrict__ gW3pad,
                                float* __restrict__ b1cat, float* __restrict__ b2cat) {
  int t = blockIdx.x * 256 + threadIdx.x;
  if (t < 65536) {
    // eW3t[e][l][k] = eW3[e][k][l]  (e<8, l<32, k<256); writes coalesced
    int e = t >> 13, i = t & 8191, l = i >> 8, k = i & 255;
    eW3t[t] = f2bf(eW3[e * 8192 + k * 32 + l]);
  } else if (t < 65536 + 4096) {
    int u = t - 65536;
    int e = u >> 8, k = u & 255;
    gW3pad[u] = (e < 8) ? f2bf(gW3[k * 8 + e]) : (short)0;
  } else if (t < 65536 + 4096 + 4608) {
    int u = t - 65536 - 4096;
    b1cat[u] = u < 512 ? gb1[u] : eb1[u - 512];
  } else if (t < 65536 + 4096 + 4608 + 2304) {
    int u = t - 65536 - 4096 - 4608;
    b2cat[u] = u < 256 ? gb2[u] : eb2[u - 256];
  }
}

#define BARRIER() asm volatile("s_barrier" ::: "memory")

// ---------------- 8-phase staging: one operand half-tile ----------------
template <int ROWS>
DEVI void stage_half8(const short* __restrict__ g, int ld, int row0, int kt, int h,
                      short* ldsop, int wave, int lane) {
  constexpr int CPW = ROWS / 128;
  const int r_in = lane >> 3, c = lane & 7;
#pragma unroll
  for (int i = 0; i < CPW; ++i) {
    const int ch = h * (ROWS / 16) + wave * CPW + i;
    const int r = ch * 8 + r_in;
    const int cs = c ^ (r & 7);
    const short* src = g + (size_t)(row0 + r) * ld + kt * 64 + cs * 8;
    __builtin_amdgcn_global_load_lds((__attribute__((address_space(1))) void*)src,
                                     (__attribute__((address_space(3))) void*)(ldsop + ch * 512),
                                     16, 0, 0);
  }
}

// ---------------- 8-phase 256xBN grouped GEMM (layer-1; verified r8/r10/r12/r15 structure) ----------------
template <int BM, int BN>
__global__ __launch_bounds__(512) void gemm8p_kernel(
    const short* __restrict__ A, const short* __restrict__ Bt,
    const float* __restrict__ bias, short* __restrict__ Cout,
    int K, int lda, int ldc, long AzOff, long BzOff, long CzOff, int BiasZOff,
    int nx, int nz) {
  constexpr int WN = BN / 4;
  constexpr int NF = WN / 16;
  constexpr int NH = NF / 2;
  constexpr int DB = (BM + BN) * 64;
  extern __shared__ __align__(16) short smem[];
  const int bid = blockIdx.x;
  const int spx = gridDim.x >> 3;
  const int lin = (bid & 7) * spx + (bid >> 3);
  const int nxz = nx * nz;
  const int by = lin / nxz, rem = lin % nxz;
  const int bz = rem / nx, bx = rem % nx;
  A += (size_t)bz * AzOff;
  Bt += (size_t)bz * BzOff;
  Cout += (size_t)bz * CzOff;
  bias += bz * BiasZOff;
  const int tid = threadIdx.x, wave = tid >> 6, lane = tid & 63;
  const int l15 = lane & 15, l4 = lane >> 4;
  const int wm = wave >> 2, wn = wave & 3;
  const int brow = by * BM, bcol = bx * BN;
  const int NT = K / 64;

  auto FR = [&](const short* base, int r, int kc) {
    return *(const shortx8*)(base + r * 64 + ((kc ^ (r & 7)) << 3));
  };

  floatx4 acc[8][NF] = {};
  shortx8 af[4][2], bq[NF][2];

  {
    short* a0 = smem;            short* b0 = smem + BM * 64;
    short* a1 = smem + DB;       short* b1 = smem + DB + BM * 64;
    stage_half8<BM>(A, lda, brow, 0, 0, a0, wave, lane);
    stage_half8<BM>(A, lda, brow, 0, 1, a0, wave, lane);
    stage_half8<BN>(Bt, K, bcol, 0, 0, b0, wave, lane);
    stage_half8<BN>(Bt, K, bcol, 0, 1, b0, wave, lane);
    if (NT > 1) {
      stage_half8<BN>(Bt, K, bcol, 1, 0, b1, wave, lane);
      stage_half8<BM>(A, lda, brow, 1, 0, a1, wave, lane);
      if constexpr (BN == 256) asm volatile("s_waitcnt vmcnt(4)" ::: "memory");
      else                     asm volatile("s_waitcnt vmcnt(3)" ::: "memory");
    } else {
      asm volatile("s_waitcnt vmcnt(0)" ::: "memory");
    }
    BARRIER();
  }

  for (int kt = 0; kt < NT; ++kt) {
    const int cur = kt & 1;
    const short* la = smem + cur * DB;
    const short* lb = la + BM * 64;
    short* an = smem + (cur ^ 1) * DB;
    short* bn = an + BM * 64;
    short* ac = smem + cur * DB;
    short* bc = ac + BM * 64;

#pragma unroll
    for (int m2 = 0; m2 < 4; ++m2) {
      const int r = wm * 128 + m2 * 16 + l15;
#pragma unroll
      for (int ks = 0; ks < 2; ++ks) af[m2][ks] = FR(la, r, ks * 4 + l4);
    }
#pragma unroll
    for (int n2 = 0; n2 < NH; ++n2) {
      const int r = wn * WN + n2 * 16 + l15;
#pragma unroll
      for (int ks = 0; ks < 2; ++ks) bq[n2][ks] = FR(lb, r, ks * 4 + l4);
    }
    if (kt + 1 < NT) stage_half8<BM>(A, lda, brow, kt + 1, 1, an, wave, lane);
    BARRIER();
    __builtin_amdgcn_s_setprio(1);
#pragma unroll
    for (int m2 = 0; m2 < 4; ++m2)
#pragma unroll
      for (int n2 = 0; n2 < NH; ++n2)
#pragma unroll
        for (int ks = 0; ks < 2; ++ks)
          acc[m2][n2] = __builtin_amdgcn_mfma_f32_16x16x32_bf16(af[m2][ks], bq[n2][ks],
                                                                acc[m2][n2], 0, 0, 0);
    __builtin_amdgcn_s_setprio(0);
    BARRIER();

#pragma unroll
    for (int n2 = 0; n2 < NH; ++n2) {
      const int r = wn * WN + (NH + n2) * 16 + l15;
#pragma unroll
      for (int ks = 0; ks < 2; ++ks) bq[NH + n2][ks] = FR(lb, r, ks * 4 + l4);
    }
    if (kt + 1 < NT) stage_half8<BN>(Bt, K, bcol, kt + 1, 1, bn, wave, lane);
    BARRIER();
    __builtin_amdgcn_s_setprio(1);
#pragma unroll
    for (int m2 = 0; m2 < 4; ++m2)
#pragma unroll
      for (int n2 = 0; n2 < NH; ++n2)
#pragma unroll
        for (int ks = 0; ks < 2; ++ks)
          acc[m2][NH + n2] = __builtin_amdgcn_mfma_f32_16x16x32_bf16(af[m2][ks], bq[NH + n2][ks],
                                                                     acc[m2][NH + n2], 0, 0, 0);
    __builtin_amdgcn_s_setprio(0);
    BARRIER();

#pragma unroll
    for (int m2 = 0; m2 < 4; ++m2) {
      const int r = wm * 128 + (4 + m2) * 16 + l15;
#pragma unroll
      for (int ks = 0; ks < 2; ++ks) af[m2][ks] = FR(la, r, ks * 4 + l4);
    }
    if (kt + 2 < NT) stage_half8<BN>(Bt, K, bcol, kt + 2, 0, bc, wave, lane);
    BARRIER();
    __builtin_amdgcn_s_setprio(1);
#pragma unroll
    for (int m2 = 0; m2 < 4; ++m2)
#pragma unroll
      for (int n2 = 0; n2 < NH; ++n2)
#pragma unroll
        for (int ks = 0; ks < 2; ++ks)
          acc[4 + m2][n2] = __builtin_amdgcn_mfma_f32_16x16x32_bf16(af[m2][ks], bq[n2][ks],
                                                                    acc[4 + m2][n2], 0, 0, 0);
    __builtin_amdgcn_s_setprio(0);
    BARRIER();

    if (kt + 2 < NT) stage_half8<BM>(A, lda, brow, kt + 2, 0, ac, wave, lane);
    BARRIER();
    __builtin_amdgcn_s_setprio(1);
#pragma unroll
    for (int m2 = 0; m2 < 4; ++m2)
#pragma unroll
      for (int n2 = 0; n2 < NH; ++n2)
#pragma unroll
        for (int ks = 0; ks < 2; ++ks)
          acc[4 + m2][NH + n2] = __builtin_amdgcn_mfma_f32_16x16x32_bf16(
              af[m2][ks], bq[NH + n2][ks], acc[4 + m2][NH + n2], 0, 0, 0);
    __builtin_amdgcn_s_setprio(0);
    if (kt + 1 < NT) {
      if (kt == NT - 2) {
        asm volatile("s_waitcnt vmcnt(0)" ::: "memory");
      } else {
        if constexpr (BN == 256) asm volatile("s_waitcnt vmcnt(4)" ::: "memory");
        else                     asm volatile("s_waitcnt vmcnt(3)" ::: "memory");
      }
      BARRIER();
    }
  }

  // epilogue: scalar ELU + bf16 stores (r12/r15-verified; stores are fire-and-forget,
  // r14 proved an LDS repack here costs more than it saves — bank conflicts)
#pragma unroll
  for (int m2 = 0; m2 < 8; ++m2) {
    const int row0 = brow + wm * 128 + m2 * 16 + l4 * 4;
#pragma unroll
    for (int n2 = 0; n2 < NF; ++n2) {
      const int col = bcol + wn * WN + n2 * 16 + l15;
      const float bv = bias[col];
#pragma unroll
      for (int r = 0; r < 4; ++r) {
        float v = acc[m2][n2][r] + bv;
        v = v > 0.f ? v : (__expf(v) - 1.f);  // ELU
        Cout[(size_t)(row0 + r) * ldc + col] = f2bf(v);
      }
    }
  }
}

// ---------------- fused layer-2 + layer-3 + gate3 kernel (BM=256, BN=256, K=512) ----------------
__global__ __launch_bounds__(512) void gemm8p_l2l3_kernel(
    const short* __restrict__ A, const short* __restrict__ Bt,
    const float* __restrict__ bias,
    const short* __restrict__ w3, const float* __restrict__ b3,
    const short* __restrict__ gw3pad, const float* __restrict__ gb3,
    float* __restrict__ elat, float* __restrict__ outW,
    int gBase, int nz, int lda) {
  constexpr int BM = 256, BN = 256, KT = 512;
  constexpr int NH = 2, DB = (BM + BN) * 64, NT = KT / 64;
  extern __shared__ __align__(16) short smem[];
  const int bid = blockIdx.x;
  const int spx = gridDim.x >> 3;
  const int lin = (bid & 7) * spx + (bid >> 3);
  const int by = lin / nz, bz = lin % nz;   // z-innermost on each XCD
  A += (size_t)bz * 512;                    // buf1 column offset
  Bt += (size_t)bz * 256 * 512;
  bias += bz * 256;
  const int tid = threadIdx.x, wave = tid >> 6, lane = tid & 63;
  const int l15 = lane & 15, l4 = lane >> 4;
  const int wm = wave >> 2, wn = wave & 3;
  const int brow = by * BM;

  auto FR = [&](const short* base, int r, int kc) {
    return *(const shortx8*)(base + r * 64 + ((kc ^ (r & 7)) << 3));
  };

  floatx4 acc[8][4] = {};
  shortx8 af[4][2], bq[4][2];

  {
    short* a0 = smem;            short* b0 = smem + BM * 64;
    short* a1 = smem + DB;       short* b1 = smem + DB + BM * 64;
    stage_half8<BM>(A, lda, brow, 0, 0, a0, wave, lane);
    stage_half8<BM>(A, lda, brow, 0, 1, a0, wave, lane);
    stage_half8<BN>(Bt, KT, 0, 0, 0, b0, wave, lane);
    stage_half8<BN>(Bt, KT, 0, 0, 1, b0, wave, lane);
    stage_half8<BN>(Bt, KT, 0, 1, 0, b1, wave, lane);
    stage_half8<BM>(A, lda, brow, 1, 0, a1, wave, lane);
    asm volatile("s_waitcnt vmcnt(4)" ::: "memory");
    BARRIER();
  }

  for (int kt = 0; kt < NT; ++kt) {
    const int cur = kt & 1;
    const short* la = smem + cur * DB;
    const short* lb = la + BM * 64;
    short* an = smem + (cur ^ 1) * DB;
    short* bn = an + BM * 64;
    short* ac = smem + cur * DB;
    short* bc = ac + BM * 64;

#pragma unroll
    for (int m2 = 0; m2 < 4; ++m2) {
      const int r = wm * 128 + m2 * 16 + l15;
#pragma unroll
      for (int ks = 0; ks < 2; ++ks) af[m2][ks] = FR(la, r, ks * 4 + l4);
    }
#pragma unroll
    for (int n2 = 0; n2 < NH; ++n2) {
      const int r = wn * 64 + n2 * 16 + l15;
#pragma unroll
      for (int ks = 0; ks < 2; ++ks) bq[n2][ks] = FR(lb, r, ks * 4 + l4);
    }
    if (kt + 1 < NT) stage_half8<BM>(A, lda, brow, kt + 1, 1, an, wave, lane);
    BARRIER();
    __builtin_amdgcn_s_setprio(1);
#pragma unroll
    for (int m2 = 0; m2 < 4; ++m2)
#pragma unroll
      for (int n2 = 0; n2 < NH; ++n2)
#pragma unroll
        for (int ks = 0; ks < 2; ++ks)
          acc[m2][n2] = __builtin_amdgcn_mfma_f32_16x16x32_bf16(af[m2][ks], bq[n2][ks],
                                                                acc[m2][n2], 0, 0, 0);
    __builtin_amdgcn_s_setprio(0);
    BARRIER();

#pragma unroll
    for (int n2 = 0; n2 < NH; ++n2) {
      const int r = wn * 64 + (NH + n2) * 16 + l15;
#pragma unroll
      for (int ks = 0; ks < 2; ++ks) bq[NH + n2][ks] = FR(lb, r, ks * 4 + l4);
    }
    if (kt + 1 < NT) stage_half8<BN>(Bt, KT, 0, kt + 1, 1, bn, wave, lane);
    BARRIER();
    __builtin_amdgcn_s_setprio(1);
#pragma unroll
    for (int m2 = 0; m2 < 4; ++m2)
#pragma unroll
      for (int n2 = 0; n2 < NH; ++n2)
#pragma unroll
        for (int ks = 0; ks < 2; ++ks)
          acc[m2][NH + n2] = __builtin_amdgcn_mfma_f32_16x16x32_bf16(af[m2][ks], bq[NH + n2][ks],
                                                                     acc[m2][NH + n2], 0, 0, 0);
    __builtin_amdgcn_s_setprio(0);
    BARRIER();

#pragma unroll
    for (int m2 = 0; m2 < 4; ++m2) {
      const int r = wm * 128 + (4 + m2) * 16 + l15;
#pragma unroll
      for (int ks = 0; ks < 2; ++ks) af[m2][ks] = FR(la, r, ks * 4 + l4);
    }
    if (kt + 2 < NT) stage_half8<BN>(Bt, KT, 0, kt + 2, 0, bc, wave, lane);
    BARRIER();
    __builtin_amdgcn_s_setprio(1);
#pragma unroll
    for (int m2 = 0; m2 < 4; ++m2)
#pragma unroll
      for (int n2 = 0; n2 < NH; ++n2)
#pragma unroll
        for (int ks = 0; ks < 2; ++ks)
          acc[4 + m2][n2] = __builtin_amdgcn_mfma_f32_16x16x32_bf16(af[m2][ks], bq[n2][ks],
                                                                    acc[4 + m2][n2], 0, 0, 0);
    __builtin_amdgcn_s_setprio(0);
    BARRIER();

    if (kt + 2 < NT) stage_half8<BM>(A, lda, brow, kt + 2, 0, ac, wave, lane);
    BARRIER();
    __builtin_amdgcn_s_setprio(1);
#pragma unroll
    for (int m2 = 0; m2 < 4; ++m2)
#pragma unroll
      for (int n2 = 0; n2 < NH; ++n2)
#pragma unroll
        for (int ks = 0; ks < 2; ++ks)
          acc[4 + m2][NH + n2] = __builtin_amdgcn_mfma_f32_16x16x32_bf16(
              af[m2][ks], bq[NH + n2][ks], acc[4 + m2][NH + n2], 0, 0, 0);
    __builtin_amdgcn_s_setprio(0);
    if (kt + 1 < NT) {
      if (kt == NT - 2) asm volatile("s_waitcnt vmcnt(0)" ::: "memory");
      else               asm volatile("s_waitcnt vmcnt(4)" ::: "memory");
      BARRIER();
    }
  }

  // ---- ELU -> bf16 X2 into LDS ([256][264] pad) — both paths ----
  constexpr int XS = 264;
  short* X = smem;
#pragma unroll
  for (int m2 = 0; m2 < 8; ++m2) {
    const int rw = wm * 128 + m2 * 16 + l4 * 4;
#pragma unroll
    for (int n2 = 0; n2 < 4; ++n2) {
      const int col = wn * 64 + n2 * 16 + l15;
      const float bv = bias[col];
#pragma unroll
      for (int r = 0; r < 4; ++r) {
        float v = acc[m2][n2][r] + bv;
        v = v > 0.f ? v : (__expf(v) - 1.f);
        X[(rw + r) * XS + col] = f2bf(v);
      }
    }
  }
  BARRIER();

  const int grp = gBase + bz;
  if (grp == 0) {
    // gating: logits = X2 @ gW3^T (+gb3), softmax over e=0..7  -> outW
    floatx4 lg[2] = {};
#pragma unroll
    for (int ks = 0; ks < 8; ++ks) {
      const int kc = ks * 4 + l4;
      shortx8 xa[2];
#pragma unroll
      for (int mi = 0; mi < 2; ++mi) {
        const int rw = wave * 32 + mi * 16 + l15;
        xa[mi] = *(const shortx8*)(X + rw * XS + kc * 8);
      }
      shortx8 wb = *(const shortx8*)(gw3pad + l15 * 256 + kc * 8);
#pragma unroll
      for (int mi = 0; mi < 2; ++mi)
        lg[mi] = __builtin_amdgcn_mfma_f32_16x16x32_bf16(xa[mi], wb, lg[mi], 0, 0, 0);
    }
    const float bg = gb3[l15 & 7];
#pragma unroll
    for (int mi = 0; mi < 2; ++mi) {
#pragma unroll
      for (int r = 0; r < 4; ++r) {
        float lv = lg[mi][r] + bg;
        float m = lv;
#pragma unroll
        for (int off = 1; off < 8; off <<= 1) m = fmaxf(m, __shfl_xor(m, off));
        float p = __expf(lv - m);
        float s = p;
#pragma unroll
        for (int off = 1; off < 8; off <<= 1) s += __shfl_xor(s, off);
        if (l15 < 8) {
          const int row = brow + wave * 32 + mi * 16 + l4 * 4 + r;
          outW[(size_t)row * 8 + l15] = p / s;
        }
      }
    }
    return;
  }

  // expert: per-wave 32-row L3 GEMM (K=256)
  const int e = grp - 1;
  const short* w3e = w3 + (size_t)e * 32 * 256;
  floatx4 a2[2][2] = {};
#pragma unroll
  for (int ks = 0; ks < 8; ++ks) {
    const int kc = ks * 4 + l4;
    shortx8 xa[2], wb[2];
#pragma unroll
    for (int mi = 0; mi < 2; ++mi) {
      const int rw = wave * 32 + mi * 16 + l15;
      xa[mi] = *(const shortx8*)(X + rw * XS + kc * 8);
    }
#pragma unroll
    for (int ni = 0; ni < 2; ++ni)
      wb[ni] = *(const shortx8*)(w3e + (ni * 16 + l15) * 256 + kc * 8);
#pragma unroll
    for (int mi = 0; mi < 2; ++mi)
#pragma unroll
      for (int ni = 0; ni < 2; ++ni)
        a2[mi][ni] = __builtin_amdgcn_mfma_f32_16x16x32_bf16(xa[mi], wb[ni], a2[mi][ni], 0, 0, 0);
  }
#pragma unroll
  for (int mi = 0; mi < 2; ++mi) {
#pragma unroll
    for (int ni = 0; ni < 2; ++ni) {
      const int col = ni * 16 + l15;
      const float bv = b3[e * 32 + col];
#pragma unroll
      for (int r = 0; r < 4; ++r) {
        const int row = brow + wave * 32 + mi * 16 + l4 * 4 + r;
        elat[(size_t)row * 256 + e * 32 + col] = a2[mi][ni][r] + bv;
      }
    }
  }
}

// ---------------- gated combine + L2 normalize: thread = (b,l) ----------------
__global__ void combine_norm_kernel(const float* __restrict__ elat,
                                    const float* __restrict__ gate,
                                    float* __restrict__ out) {
  int t = blockIdx.x * 256 + threadIdx.x;
  int b = t >> 5, l = t & 31;
  const float* er = elat + (size_t)b * 256;
  const float* gr = gate + (size_t)b * 8;
  float v = 0.f;
#pragma unroll
  for (int e = 0; e < 8; ++e) v += gr[e] * er[e * 32 + l];
  float ss = v * v;
#pragma unroll
  for (int off = 1; off < 32; off <<= 1) ss += __shfl_xor(ss, off, 32);
  out[t] = v / fmaxf(sqrtf(ss), 1e-12f);
}

extern "C" void kernel_launch(void* const* d_in, const int* in_sizes, int n_in,
                              void* d_out, int out_size, void* d_ws, size_t ws_size,
                              hipStream_t stream) {
  // defensive input remap by element-count signature (identity under dict order)
  static const int kExp[14] = {16777216, 16777216, 2097152, 4096, 1048576, 2048, 65536, 256,
                               262144, 512, 131072, 256, 2048, 8};
  const void* in[14];
  bool identity = (n_in >= 14);
  if (identity)
    for (int i = 0; i < 14; ++i)
      if (in_sizes[i] != kExp[i]) { identity = false; break; }
  if (identity) {
    for (int i = 0; i < 14; ++i) in[i] = d_in[i];
  } else {
    bool used[64] = {};
    for (int i = 0; i < 14; ++i) {
      in[i] = d_in[i < n_in ? i : 0];
      for (int j = 0; j < n_in && j < 64; ++j)
        if (!used[j] && in_sizes[j] == kExp[i]) { in[i] = d_in[j]; used[j] = true; break; }
    }
  }
  const float* obs = (const float*)in[0];
  const float* eW1 = (const float*)in[2];
  const float* eb1 = (const float*)in[3];
  const float* eW2 = (const float*)in[4];
  const float* eb2 = (const float*)in[5];
  const float* eW3 = (const float*)in[6];
  const float* eb3 = (const float*)in[7];
  const float* gW1 = (const float*)in[8];
  const float* gb1 = (const float*)in[9];
  const float* gW2 = (const float*)in[10];
  const float* gb2 = (const float*)in[11];
  const float* gW3 = (const float*)in[12];
  const float* gb3 = (const float*)in[13];

  char* ws = (char*)d_ws;
  size_t off = 0;
  auto carve = [&](size_t bytes) {
    char* p = ws + off;
    off += (bytes + 255) & ~(size_t)255;
    return p;
  };
  // groups ordered [gating, e0..e7]; 2 batches {5,4}; total ws ~242 MB (< 256 MiB)
  short* obs_bf = (short*)carve((size_t)Bsz * Din * 2);
  short* w1cat = (short*)carve((size_t)4608 * 512 * 2);   // [g+8e out-rows][K=512]
  short* w2cat = (short*)carve((size_t)2304 * 512 * 2);
  short* eW3t = (short*)carve((size_t)NE * Lout * H2 * 2);
  short* gW3pad = (short*)carve((size_t)16 * H2 * 2);     // rows 0-7 = gW3^T; 8-15 zero
  float* b1cat = (float*)carve(4608 * 4);
  float* b2cat = (float*)carve(2304 * 4);
  float* elat = (float*)carve((size_t)Bsz * 256 * 4);     // [B][E*32] f32
  short* buf1 = (short*)carve((size_t)Bsz * 2560 * 2);    // [B][5*512] (batch max)

  float* out_lat = (float*)d_out;                      // [B][32] f32
  float* out_w = (float*)d_out + (size_t)Bsz * Lout;   // [B][8]  f32

  constexpr int kLds1 = 2 * (256 + 256) * 64 * 2;  // 128 KiB
  constexpr int kLdsF = 256 * 264 * 2;             // 132 KiB
  (void)hipFuncSetAttribute((const void*)gemm8p_kernel<256, 256>,
                            hipFuncAttributeMaxDynamicSharedMemorySize, kLds1);
  (void)hipFuncSetAttribute((const void*)gemm8p_l2l3_kernel,
                            hipFuncAttributeMaxDynamicSharedMemorySize, kLdsF);

  // prep: cast + merged W1/W2 transpose + merged small prep (3 launches)
  cast_bf16_kernel<<<2048, 256, 0, stream>>>(obs, obs_bf, Bsz * Din / 4);
  transpose_w12_kernel<<<dim3(16, 16, 18), dim3(32, 8), 0, stream>>>(
      gW1, eW1, gW2, eW2, w1cat, w2cat);
  prep_all_kernel<<<299, 256, 0, stream>>>(eW3, gW3, gb1, eb1, gb2, eb2,
                                           eW3t, gW3pad, b1cat, b2cat);

  // batch 0: groups {g, e0..e3} (nz=5); batch 1: {e4..e7} (nz=4)
  gemm8p_kernel<256, 256><<<1280, 512, kLds1, stream>>>(
      obs_bf, w1cat, b1cat, buf1,
      512, 512, 2560, 0L, 512L * 512, 512L, 512, 2, 5);
  gemm8p_l2l3_kernel<<<640, 512, kLdsF, stream>>>(
      buf1, w2cat, b2cat, eW3t, eb3, gW3pad, gb3, elat, out_w, 0, 5, 2560);

  gemm8p_kernel<256, 256><<<1024, 512, kLds1, stream>>>(
      obs_bf, w1cat + (size_t)5 * 512 * 512, b1cat + 2560, buf1,
      512, 512, 2048, 0L, 512L * 512, 512L, 512, 2, 4);
  gemm8p_l2l3_kernel<<<512, 512, kLdsF, stream>>>(
      buf1, w2cat + (size_t)5 * 256 * 512, b2cat + 1280, eW3t, eb3, gW3pad, gb3,
      elat, out_w, 5, 4, 2048);

  combine_norm_kernel<<<(Bsz * Lout) / 256, 256, 0, stream>>>(elat, out_w, out_lat);
}

// Round 19
// 326.045 us; speedup vs baseline: 1.0737x; 1.0099x over previous
//
#include <hip/hip_runtime.h>
#include <hip/hip_bf16.h>

#define DEVI __device__ __forceinline__

typedef __attribute__((ext_vector_type(8))) short shortx8;
typedef __attribute__((ext_vector_type(4))) float floatx4;

static constexpr int Bsz = 32768, Din = 512, H1 = 512, H2 = 256, NE = 8, Lout = 32;

DEVI float bf2f(short s) {
  union { unsigned u; float f; } c;
  c.u = ((unsigned)(unsigned short)s) << 16;
  return c.f;
}
// round-to-nearest-even f32 -> bf16 (finite inputs only)
DEVI short f2bf(float f) {
  union { float f; unsigned u; } c; c.f = f;
  unsigned u = c.u + (0x7FFFu + ((c.u >> 16) & 1u));
  return (short)(u >> 16);
}

// ---------------- elementwise cast f32 -> bf16 ----------------
__global__ void cast_bf16_kernel(const float* __restrict__ in, short* __restrict__ out, int n4) {
  int stride = gridDim.x * blockDim.x;
  for (int i = blockIdx.x * blockDim.x + threadIdx.x; i < n4; i += stride) {
    float4 v = ((const float4*)in)[i];
    short4 o;
    o.x = f2bf(v.x); o.y = f2bf(v.y); o.z = f2bf(v.z); o.w = f2bf(v.w);
    ((short4*)out)[i] = o;
  }
}

// ---------------- merged W1+W2 transpose: z<9 -> W1 piece, z>=9 -> W2 piece ----------------
// dst layout per group: [C][R] bf16 (B^T form for the GEMM)
__global__ void transpose_w12_kernel(const float* __restrict__ gW1, const float* __restrict__ eW1,
                                     const float* __restrict__ gW2, const float* __restrict__ eW2,
                                     short* __restrict__ w1cat, short* __restrict__ w2cat) {
  __shared__ short tile[32][33];
  const int z = blockIdx.z;
  const float* in;
  short* out;
  int R, C;
  if (z < 9) {
    R = 512; C = 512;
    in = z ? eW1 + (size_t)(z - 1) * 262144 : gW1;
    out = w1cat + (size_t)z * 262144;
  } else {
    R = 512; C = 256;
    if (blockIdx.x >= 8) return;  // uniform per-block, before any barrier
    const int zz = z - 9;
    in = zz ? eW2 + (size_t)(zz - 1) * 131072 : gW2;
    out = w2cat + (size_t)zz * 131072;
  }
  int c0 = blockIdx.x * 32, r0 = blockIdx.y * 32;
  int tx = threadIdx.x, ty = threadIdx.y;
#pragma unroll
  for (int i = 0; i < 4; ++i) {
    int r = r0 + ty + i * 8, c = c0 + tx;
    tile[ty + i * 8][tx] = f2bf(in[(size_t)r * C + c]);
  }
  __syncthreads();
#pragma unroll
  for (int i = 0; i < 4; ++i) {
    int c = c0 + ty + i * 8, r = r0 + tx;
    out[(size_t)c * R + r] = tile[tx][ty + i * 8];
  }
}

// ---------------- merged small prep: eW3t + gW3pad + bias concats (76544 threads) ----------------
__global__ void prep_all_kernel(const float* __restrict__ eW3, const float* __restrict__ gW3,
                                const float* __restrict__ gb1, const float* __restrict__ eb1,
                                const float* __restrict__ gb2, const float* __restrict__ eb2,
                                short* __restrict__ eW3t, short* __restrict__ gW3pad,
                                float* __restrict__ b1cat, float* __restrict__ b2cat) {
  int t = blockIdx.x * 256 + threadIdx.x;
  if (t < 65536) {
    // eW3t[e][l][k] = eW3[e][k][l]  (e<8, l<32, k<256); writes coalesced
    int e = t >> 13, i = t & 8191, l = i >> 8, k = i & 255;
    eW3t[t] = f2bf(eW3[e * 8192 + k * 32 + l]);
  } else if (t < 65536 + 4096) {
    int u = t - 65536;
    int e = u >> 8, k = u & 255;
    gW3pad[u] = (e < 8) ? f2bf(gW3[k * 8 + e]) : (short)0;
  } else if (t < 65536 + 4096 + 4608) {
    int u = t - 65536 - 4096;
    b1cat[u] = u < 512 ? gb1[u] : eb1[u - 512];
  } else if (t < 65536 + 4096 + 4608 + 2304) {
    int u = t - 65536 - 4096 - 4608;
    b2cat[u] = u < 256 ? gb2[u] : eb2[u - 256];
  }
}

#define BARRIER() asm volatile("s_barrier" ::: "memory")

// ---------------- 8-phase staging: one operand half-tile ----------------
template <int ROWS>
DEVI void stage_half8(const short* __restrict__ g, int ld, int row0, int kt, int h,
                      short* ldsop, int wave, int lane) {
  constexpr int CPW = ROWS / 128;
  const int r_in = lane >> 3, c = lane & 7;
#pragma unroll
  for (int i = 0; i < CPW; ++i) {
    const int ch = h * (ROWS / 16) + wave * CPW + i;
    const int r = ch * 8 + r_in;
    const int cs = c ^ (r & 7);
    const short* src = g + (size_t)(row0 + r) * ld + kt * 64 + cs * 8;
    __builtin_amdgcn_global_load_lds((__attribute__((address_space(1))) void*)src,
                                     (__attribute__((address_space(3))) void*)(ldsop + ch * 512),
                                     16, 0, 0);
  }
}

// ---------------- 8-phase 256xBN grouped GEMM (layer-1; verified r8/r10/r12/r15 structure) ----------------
template <int BM, int BN>
__global__ __launch_bounds__(512) void gemm8p_kernel(
    const short* __restrict__ A, const short* __restrict__ Bt,
    const float* __restrict__ bias, short* __restrict__ Cout,
    int K, int lda, int ldc, long AzOff, long BzOff, long CzOff, int BiasZOff,
    int nx, int nz) {
  constexpr int WN = BN / 4;
  constexpr int NF = WN / 16;
  constexpr int NH = NF / 2;
  constexpr int DB = (BM + BN) * 64;
  extern __shared__ __align__(16) short smem[];
  const int bid = blockIdx.x;
  const int spx = gridDim.x >> 3;
  const int lin = (bid & 7) * spx + (bid >> 3);
  const int nxz = nx * nz;
  const int by = lin / nxz, rem = lin % nxz;
  const int bz = rem / nx, bx = rem % nx;
  A += (size_t)bz * AzOff;
  Bt += (size_t)bz * BzOff;
  Cout += (size_t)bz * CzOff;
  bias += bz * BiasZOff;
  const int tid = threadIdx.x, wave = tid >> 6, lane = tid & 63;
  const int l15 = lane & 15, l4 = lane >> 4;
  const int wm = wave >> 2, wn = wave & 3;
  const int brow = by * BM, bcol = bx * BN;
  const int NT = K / 64;

  auto FR = [&](const short* base, int r, int kc) {
    return *(const shortx8*)(base + r * 64 + ((kc ^ (r & 7)) << 3));
  };

  floatx4 acc[8][NF] = {};
  shortx8 af[4][2], bq[NF][2];

  {
    short* a0 = smem;            short* b0 = smem + BM * 64;
    short* a1 = smem + DB;       short* b1 = smem + DB + BM * 64;
    stage_half8<BM>(A, lda, brow, 0, 0, a0, wave, lane);
    stage_half8<BM>(A, lda, brow, 0, 1, a0, wave, lane);
    stage_half8<BN>(Bt, K, bcol, 0, 0, b0, wave, lane);
    stage_half8<BN>(Bt, K, bcol, 0, 1, b0, wave, lane);
    if (NT > 1) {
      stage_half8<BN>(Bt, K, bcol, 1, 0, b1, wave, lane);
      stage_half8<BM>(A, lda, brow, 1, 0, a1, wave, lane);
      if constexpr (BN == 256) asm volatile("s_waitcnt vmcnt(4)" ::: "memory");
      else                     asm volatile("s_waitcnt vmcnt(3)" ::: "memory");
    } else {
      asm volatile("s_waitcnt vmcnt(0)" ::: "memory");
    }
    BARRIER();
  }

  for (int kt = 0; kt < NT; ++kt) {
    const int cur = kt & 1;
    const short* la = smem + cur * DB;
    const short* lb = la + BM * 64;
    short* an = smem + (cur ^ 1) * DB;
    short* bn = an + BM * 64;
    short* ac = smem + cur * DB;
    short* bc = ac + BM * 64;

#pragma unroll
    for (int m2 = 0; m2 < 4; ++m2) {
      const int r = wm * 128 + m2 * 16 + l15;
#pragma unroll
      for (int ks = 0; ks < 2; ++ks) af[m2][ks] = FR(la, r, ks * 4 + l4);
    }
#pragma unroll
    for (int n2 = 0; n2 < NH; ++n2) {
      const int r = wn * WN + n2 * 16 + l15;
#pragma unroll
      for (int ks = 0; ks < 2; ++ks) bq[n2][ks] = FR(lb, r, ks * 4 + l4);
    }
    if (kt + 1 < NT) stage_half8<BM>(A, lda, brow, kt + 1, 1, an, wave, lane);
    BARRIER();
    __builtin_amdgcn_s_setprio(1);
#pragma unroll
    for (int m2 = 0; m2 < 4; ++m2)
#pragma unroll
      for (int n2 = 0; n2 < NH; ++n2)
#pragma unroll
        for (int ks = 0; ks < 2; ++ks)
          acc[m2][n2] = __builtin_amdgcn_mfma_f32_16x16x32_bf16(af[m2][ks], bq[n2][ks],
                                                                acc[m2][n2], 0, 0, 0);
    __builtin_amdgcn_s_setprio(0);
    BARRIER();

#pragma unroll
    for (int n2 = 0; n2 < NH; ++n2) {
      const int r = wn * WN + (NH + n2) * 16 + l15;
#pragma unroll
      for (int ks = 0; ks < 2; ++ks) bq[NH + n2][ks] = FR(lb, r, ks * 4 + l4);
    }
    if (kt + 1 < NT) stage_half8<BN>(Bt, K, bcol, kt + 1, 1, bn, wave, lane);
    BARRIER();
    __builtin_amdgcn_s_setprio(1);
#pragma unroll
    for (int m2 = 0; m2 < 4; ++m2)
#pragma unroll
      for (int n2 = 0; n2 < NH; ++n2)
#pragma unroll
        for (int ks = 0; ks < 2; ++ks)
          acc[m2][NH + n2] = __builtin_amdgcn_mfma_f32_16x16x32_bf16(af[m2][ks], bq[NH + n2][ks],
                                                                     acc[m2][NH + n2], 0, 0, 0);
    __builtin_amdgcn_s_setprio(0);
    BARRIER();

#pragma unroll
    for (int m2 = 0; m2 < 4; ++m2) {
      const int r = wm * 128 + (4 + m2) * 16 + l15;
#pragma unroll
      for (int ks = 0; ks < 2; ++ks) af[m2][ks] = FR(la, r, ks * 4 + l4);
    }
    if (kt + 2 < NT) stage_half8<BN>(Bt, K, bcol, kt + 2, 0, bc, wave, lane);
    BARRIER();
    __builtin_amdgcn_s_setprio(1);
#pragma unroll
    for (int m2 = 0; m2 < 4; ++m2)
#pragma unroll
      for (int n2 = 0; n2 < NH; ++n2)
#pragma unroll
        for (int ks = 0; ks < 2; ++ks)
          acc[4 + m2][n2] = __builtin_amdgcn_mfma_f32_16x16x32_bf16(af[m2][ks], bq[n2][ks],
                                                                    acc[4 + m2][n2], 0, 0, 0);
    __builtin_amdgcn_s_setprio(0);
    BARRIER();

    if (kt + 2 < NT) stage_half8<BM>(A, lda, brow, kt + 2, 0, ac, wave, lane);
    BARRIER();
    __builtin_amdgcn_s_setprio(1);
#pragma unroll
    for (int m2 = 0; m2 < 4; ++m2)
#pragma unroll
      for (int n2 = 0; n2 < NH; ++n2)
#pragma unroll
        for (int ks = 0; ks < 2; ++ks)
          acc[4 + m2][NH + n2] = __builtin_amdgcn_mfma_f32_16x16x32_bf16(
              af[m2][ks], bq[NH + n2][ks], acc[4 + m2][NH + n2], 0, 0, 0);
    __builtin_amdgcn_s_setprio(0);
    if (kt + 1 < NT) {
      if (kt == NT - 2) {
        asm volatile("s_waitcnt vmcnt(0)" ::: "memory");
      } else {
        if constexpr (BN == 256) asm volatile("s_waitcnt vmcnt(4)" ::: "memory");
        else                     asm volatile("s_waitcnt vmcnt(3)" ::: "memory");
      }
      BARRIER();
    }
  }

  // epilogue: scalar ELU + bf16 stores (r12/r15-verified; stores are fire-and-forget,
  // r14 proved an LDS repack here costs more than it saves — bank conflicts)
#pragma unroll
  for (int m2 = 0; m2 < 8; ++m2) {
    const int row0 = brow + wm * 128 + m2 * 16 + l4 * 4;
#pragma unroll
    for (int n2 = 0; n2 < NF; ++n2) {
      const int col = bcol + wn * WN + n2 * 16 + l15;
      const float bv = bias[col];
#pragma unroll
      for (int r = 0; r < 4; ++r) {
        float v = acc[m2][n2][r] + bv;
        v = v > 0.f ? v : (__expf(v) - 1.f);  // ELU
        Cout[(size_t)(row0 + r) * ldc + col] = f2bf(v);
      }
    }
  }
}

// ---------------- fused layer-2 + layer-3 + gate3 kernel (BM=256, BN=256, K=512) ----------------
__global__ __launch_bounds__(512) void gemm8p_l2l3_kernel(
    const short* __restrict__ A, const short* __restrict__ Bt,
    const float* __restrict__ bias,
    const short* __restrict__ w3, const float* __restrict__ b3,
    const short* __restrict__ gw3pad, const float* __restrict__ gb3,
    short* __restrict__ elat, float* __restrict__ outW,
    int gBase, int nz, int lda) {
  constexpr int BM = 256, BN = 256, KT = 512;
  constexpr int NH = 2, DB = (BM + BN) * 64, NT = KT / 64;
  extern __shared__ __align__(16) short smem[];
  const int bid = blockIdx.x;
  const int spx = gridDim.x >> 3;
  const int lin = (bid & 7) * spx + (bid >> 3);
  const int by = lin / nz, bz = lin % nz;   // z-innermost on each XCD
  A += (size_t)bz * 512;                    // buf1 column offset
  Bt += (size_t)bz * 256 * 512;
  bias += bz * 256;
  const int tid = threadIdx.x, wave = tid >> 6, lane = tid & 63;
  const int l15 = lane & 15, l4 = lane >> 4;
  const int wm = wave >> 2, wn = wave & 3;
  const int brow = by * BM;

  auto FR = [&](const short* base, int r, int kc) {
    return *(const shortx8*)(base + r * 64 + ((kc ^ (r & 7)) << 3));
  };

  floatx4 acc[8][4] = {};
  shortx8 af[4][2], bq[4][2];

  {
    short* a0 = smem;            short* b0 = smem + BM * 64;
    short* a1 = smem + DB;       short* b1 = smem + DB + BM * 64;
    stage_half8<BM>(A, lda, brow, 0, 0, a0, wave, lane);
    stage_half8<BM>(A, lda, brow, 0, 1, a0, wave, lane);
    stage_half8<BN>(Bt, KT, 0, 0, 0, b0, wave, lane);
    stage_half8<BN>(Bt, KT, 0, 0, 1, b0, wave, lane);
    stage_half8<BN>(Bt, KT, 0, 1, 0, b1, wave, lane);
    stage_half8<BM>(A, lda, brow, 1, 0, a1, wave, lane);
    asm volatile("s_waitcnt vmcnt(4)" ::: "memory");
    BARRIER();
  }

  for (int kt = 0; kt < NT; ++kt) {
    const int cur = kt & 1;
    const short* la = smem + cur * DB;
    const short* lb = la + BM * 64;
    short* an = smem + (cur ^ 1) * DB;
    short* bn = an + BM * 64;
    short* ac = smem + cur * DB;
    short* bc = ac + BM * 64;

#pragma unroll
    for (int m2 = 0; m2 < 4; ++m2) {
      const int r = wm * 128 + m2 * 16 + l15;
#pragma unroll
      for (int ks = 0; ks < 2; ++ks) af[m2][ks] = FR(la, r, ks * 4 + l4);
    }
#pragma unroll
    for (int n2 = 0; n2 < NH; ++n2) {
      const int r = wn * 64 + n2 * 16 + l15;
#pragma unroll
      for (int ks = 0; ks < 2; ++ks) bq[n2][ks] = FR(lb, r, ks * 4 + l4);
    }
    if (kt + 1 < NT) stage_half8<BM>(A, lda, brow, kt + 1, 1, an, wave, lane);
    BARRIER();
    __builtin_amdgcn_s_setprio(1);
#pragma unroll
    for (int m2 = 0; m2 < 4; ++m2)
#pragma unroll
      for (int n2 = 0; n2 < NH; ++n2)
#pragma unroll
        for (int ks = 0; ks < 2; ++ks)
          acc[m2][n2] = __builtin_amdgcn_mfma_f32_16x16x32_bf16(af[m2][ks], bq[n2][ks],
                                                                acc[m2][n2], 0, 0, 0);
    __builtin_amdgcn_s_setprio(0);
    BARRIER();

#pragma unroll
    for (int n2 = 0; n2 < NH; ++n2) {
      const int r = wn * 64 + (NH + n2) * 16 + l15;
#pragma unroll
      for (int ks = 0; ks < 2; ++ks) bq[NH + n2][ks] = FR(lb, r, ks * 4 + l4);
    }
    if (kt + 1 < NT) stage_half8<BN>(Bt, KT, 0, kt + 1, 1, bn, wave, lane);
    BARRIER();
    __builtin_amdgcn_s_setprio(1);
#pragma unroll
    for (int m2 = 0; m2 < 4; ++m2)
#pragma unroll
      for (int n2 = 0; n2 < NH; ++n2)
#pragma unroll
        for (int ks = 0; ks < 2; ++ks)
          acc[m2][NH + n2] = __builtin_amdgcn_mfma_f32_16x16x32_bf16(af[m2][ks], bq[NH + n2][ks],
                                                                     acc[m2][NH + n2], 0, 0, 0);
    __builtin_amdgcn_s_setprio(0);
    BARRIER();

#pragma unroll
    for (int m2 = 0; m2 < 4; ++m2) {
      const int r = wm * 128 + (4 + m2) * 16 + l15;
#pragma unroll
      for (int ks = 0; ks < 2; ++ks) af[m2][ks] = FR(la, r, ks * 4 + l4);
    }
    if (kt + 2 < NT) stage_half8<BN>(Bt, KT, 0, kt + 2, 0, bc, wave, lane);
    BARRIER();
    __builtin_amdgcn_s_setprio(1);
#pragma unroll
    for (int m2 = 0; m2 < 4; ++m2)
#pragma unroll
      for (int n2 = 0; n2 < NH; ++n2)
#pragma unroll
        for (int ks = 0; ks < 2; ++ks)
          acc[4 + m2][n2] = __builtin_amdgcn_mfma_f32_16x16x32_bf16(af[m2][ks], bq[n2][ks],
                                                                    acc[4 + m2][n2], 0, 0, 0);
    __builtin_amdgcn_s_setprio(0);
    BARRIER();

    if (kt + 2 < NT) stage_half8<BM>(A, lda, brow, kt + 2, 0, ac, wave, lane);
    BARRIER();
    __builtin_amdgcn_s_setprio(1);
#pragma unroll
    for (int m2 = 0; m2 < 4; ++m2)
#pragma unroll
      for (int n2 = 0; n2 < NH; ++n2)
#pragma unroll
        for (int ks = 0; ks < 2; ++ks)
          acc[4 + m2][NH + n2] = __builtin_amdgcn_mfma_f32_16x16x32_bf16(
              af[m2][ks], bq[NH + n2][ks], acc[4 + m2][NH + n2], 0, 0, 0);
    __builtin_amdgcn_s_setprio(0);
    if (kt + 1 < NT) {
      if (kt == NT - 2) asm volatile("s_waitcnt vmcnt(0)" ::: "memory");
      else               asm volatile("s_waitcnt vmcnt(4)" ::: "memory");
      BARRIER();
    }
  }

  // ---- ELU -> bf16 X2 into LDS ([256][264] pad) — both paths ----
  constexpr int XS = 264;
  short* X = smem;
#pragma unroll
  for (int m2 = 0; m2 < 8; ++m2) {
    const int rw = wm * 128 + m2 * 16 + l4 * 4;
#pragma unroll
    for (int n2 = 0; n2 < 4; ++n2) {
      const int col = wn * 64 + n2 * 16 + l15;
      const float bv = bias[col];
#pragma unroll
      for (int r = 0; r < 4; ++r) {
        float v = acc[m2][n2][r] + bv;
        v = v > 0.f ? v : (__expf(v) - 1.f);
        X[(rw + r) * XS + col] = f2bf(v);
      }
    }
  }
  BARRIER();

  const int grp = gBase + bz;
  if (grp == 0) {
    // gating: logits = X2 @ gW3^T (+gb3), softmax over e=0..7  -> outW
    floatx4 lg[2] = {};
#pragma unroll
    for (int ks = 0; ks < 8; ++ks) {
      const int kc = ks * 4 + l4;
      shortx8 xa[2];
#pragma unroll
      for (int mi = 0; mi < 2; ++mi) {
        const int rw = wave * 32 + mi * 16 + l15;
        xa[mi] = *(const shortx8*)(X + rw * XS + kc * 8);
      }
      shortx8 wb = *(const shortx8*)(gw3pad + l15 * 256 + kc * 8);
#pragma unroll
      for (int mi = 0; mi < 2; ++mi)
        lg[mi] = __builtin_amdgcn_mfma_f32_16x16x32_bf16(xa[mi], wb, lg[mi], 0, 0, 0);
    }
    const float bg = gb3[l15 & 7];
#pragma unroll
    for (int mi = 0; mi < 2; ++mi) {
#pragma unroll
      for (int r = 0; r < 4; ++r) {
        float lv = lg[mi][r] + bg;
        float m = lv;
#pragma unroll
        for (int off = 1; off < 8; off <<= 1) m = fmaxf(m, __shfl_xor(m, off));
        float p = __expf(lv - m);
        float s = p;
#pragma unroll
        for (int off = 1; off < 8; off <<= 1) s += __shfl_xor(s, off);
        if (l15 < 8) {
          const int row = brow + wave * 32 + mi * 16 + l4 * 4 + r;
          outW[(size_t)row * 8 + l15] = p / s;
        }
      }
    }
    return;
  }

  // expert: per-wave 32-row L3 GEMM (K=256) -> bf16 elat
  const int e = grp - 1;
  const short* w3e = w3 + (size_t)e * 32 * 256;
  floatx4 a2[2][2] = {};
#pragma unroll
  for (int ks = 0; ks < 8; ++ks) {
    const int kc = ks * 4 + l4;
    shortx8 xa[2], wb[2];
#pragma unroll
    for (int mi = 0; mi < 2; ++mi) {
      const int rw = wave * 32 + mi * 16 + l15;
      xa[mi] = *(const shortx8*)(X + rw * XS + kc * 8);
    }
#pragma unroll
    for (int ni = 0; ni < 2; ++ni)
      wb[ni] = *(const shortx8*)(w3e + (ni * 16 + l15) * 256 + kc * 8);
#pragma unroll
    for (int mi = 0; mi < 2; ++mi)
#pragma unroll
      for (int ni = 0; ni < 2; ++ni)
        a2[mi][ni] = __builtin_amdgcn_mfma_f32_16x16x32_bf16(xa[mi], wb[ni], a2[mi][ni], 0, 0, 0);
  }
#pragma unroll
  for (int mi = 0; mi < 2; ++mi) {
#pragma unroll
    for (int ni = 0; ni < 2; ++ni) {
      const int col = ni * 16 + l15;
      const float bv = b3[e * 32 + col];
#pragma unroll
      for (int r = 0; r < 4; ++r) {
        const int row = brow + wave * 32 + mi * 16 + l4 * 4 + r;
        elat[(size_t)row * 256 + e * 32 + col] = f2bf(a2[mi][ni][r] + bv);
      }
    }
  }
}

// ---------------- gated combine + L2 normalize: thread = (b,l); elat bf16 ----------------
__global__ void combine_norm_kernel(const short* __restrict__ elat,
                                    const float* __restrict__ gate,
                                    float* __restrict__ out) {
  int t = blockIdx.x * 256 + threadIdx.x;
  int b = t >> 5, l = t & 31;
  const short* er = elat + (size_t)b * 256;
  const float* gr = gate + (size_t)b * 8;
  float v = 0.f;
#pragma unroll
  for (int e = 0; e < 8; ++e) v += gr[e] * bf2f(er[e * 32 + l]);
  float ss = v * v;
#pragma unroll
  for (int off = 1; off < 32; off <<= 1) ss += __shfl_xor(ss, off, 32);
  out[t] = v / fmaxf(sqrtf(ss), 1e-12f);
}

extern "C" void kernel_launch(void* const* d_in, const int* in_sizes, int n_in,
                              void* d_out, int out_size, void* d_ws, size_t ws_size,
                              hipStream_t stream) {
  // defensive input remap by element-count signature (identity under dict order)
  static const int kExp[14] = {16777216, 16777216, 2097152, 4096, 1048576, 2048, 65536, 256,
                               262144, 512, 131072, 256, 2048, 8};
  const void* in[14];
  bool identity = (n_in >= 14);
  if (identity)
    for (int i = 0; i < 14; ++i)
      if (in_sizes[i] != kExp[i]) { identity = false; break; }
  if (identity) {
    for (int i = 0; i < 14; ++i) in[i] = d_in[i];
  } else {
    bool used[64] = {};
    for (int i = 0; i < 14; ++i) {
      in[i] = d_in[i < n_in ? i : 0];
      for (int j = 0; j < n_in && j < 64; ++j)
        if (!used[j] && in_sizes[j] == kExp[i]) { in[i] = d_in[j]; used[j] = true; break; }
    }
  }
  const float* obs = (const float*)in[0];
  const float* eW1 = (const float*)in[2];
  const float* eb1 = (const float*)in[3];
  const float* eW2 = (const float*)in[4];
  const float* eb2 = (const float*)in[5];
  const float* eW3 = (const float*)in[6];
  const float* eb3 = (const float*)in[7];
  const float* gW1 = (const float*)in[8];
  const float* gb1 = (const float*)in[9];
  const float* gW2 = (const float*)in[10];
  const float* gb2 = (const float*)in[11];
  const float* gW3 = (const float*)in[12];
  const float* gb3 = (const float*)in[13];

  char* ws = (char*)d_ws;
  size_t off = 0;
  auto carve = [&](size_t bytes) {
    char* p = ws + off;
    off += (bytes + 255) & ~(size_t)255;
    return p;
  };
  // groups ordered [gating, e0..e7]; 2 batches {5,4}; total ws ~225 MB (< 256 MiB)
  short* obs_bf = (short*)carve((size_t)Bsz * Din * 2);
  short* w1cat = (short*)carve((size_t)4608 * 512 * 2);   // [g+8e out-rows][K=512]
  short* w2cat = (short*)carve((size_t)2304 * 512 * 2);
  short* eW3t = (short*)carve((size_t)NE * Lout * H2 * 2);
  short* gW3pad = (short*)carve((size_t)16 * H2 * 2);     // rows 0-7 = gW3^T; 8-15 zero
  float* b1cat = (float*)carve(4608 * 4);
  float* b2cat = (float*)carve(2304 * 4);
  short* elat = (short*)carve((size_t)Bsz * 256 * 2);     // [B][E*32] bf16
  short* buf1 = (short*)carve((size_t)Bsz * 2560 * 2);    // [B][5*512] (batch max)

  float* out_lat = (float*)d_out;                      // [B][32] f32
  float* out_w = (float*)d_out + (size_t)Bsz * Lout;   // [B][8]  f32

  constexpr int kLds1 = 2 * (256 + 256) * 64 * 2;  // 128 KiB
  constexpr int kLdsF = 256 * 264 * 2;             // 132 KiB
  (void)hipFuncSetAttribute((const void*)gemm8p_kernel<256, 256>,
                            hipFuncAttributeMaxDynamicSharedMemorySize, kLds1);
  (void)hipFuncSetAttribute((const void*)gemm8p_l2l3_kernel,
                            hipFuncAttributeMaxDynamicSharedMemorySize, kLdsF);

  // prep: cast + merged W1/W2 transpose + merged small prep (3 launches)
  cast_bf16_kernel<<<2048, 256, 0, stream>>>(obs, obs_bf, Bsz * Din / 4);
  transpose_w12_kernel<<<dim3(16, 16, 18), dim3(32, 8), 0, stream>>>(
      gW1, eW1, gW2, eW2, w1cat, w2cat);
  prep_all_kernel<<<299, 256, 0, stream>>>(eW3, gW3, gb1, eb1, gb2, eb2,
                                           eW3t, gW3pad, b1cat, b2cat);

  // batch 0: groups {g, e0..e3} (nz=5); batch 1: {e4..e7} (nz=4)
  gemm8p_kernel<256, 256><<<1280, 512, kLds1, stream>>>(
      obs_bf, w1cat, b1cat, buf1,
      512, 512, 2560, 0L, 512L * 512, 512L, 512, 2, 5);
  gemm8p_l2l3_kernel<<<640, 512, kLdsF, stream>>>(
      buf1, w2cat, b2cat, eW3t, eb3, gW3pad, gb3, elat, out_w, 0, 5, 2560);

  gemm8p_kernel<256, 256><<<1024, 512, kLds1, stream>>>(
      obs_bf, w1cat + (size_t)5 * 512 * 512, b1cat + 2560, buf1,
      512, 512, 2048, 0L, 512L * 512, 512L, 512, 2, 4);
  gemm8p_l2l3_kernel<<<512, 512, kLdsF, stream>>>(
      buf1, w2cat + (size_t)5 * 256 * 512, b2cat + 1280, eW3t, eb3, gW3pad, gb3,
      elat, out_w, 5, 4, 2048);

  combine_norm_kernel<<<(Bsz * Lout) / 256, 256, 0, stream>>>(elat, out_w, out_lat);
}